// Round 8
// baseline (742.538 us; speedup 1.0000x reference)
//
#include <hip/hip_runtime.h>
#include <cstddef>

#define B_SZ 8
#define N_PTS 1024
#define KNN_K 20
#define CAT_C 512
#define BN_EPS 1e-5f

typedef unsigned short u16;
typedef unsigned int u32;
typedef __bf16 bf16x8 __attribute__((ext_vector_type(8)));
typedef float f32x4 __attribute__((ext_vector_type(4)));

// ---------------- transpose x (B,3,N) -> feat0 (B,N,4) (col 3 pre-zeroed) ----------------
__global__ __launch_bounds__(256) void transpose_x(const float* __restrict__ x,
                                                   float* __restrict__ feat0) {
  int t = blockIdx.x * 256 + threadIdx.x;
  if (t >= B_SZ * 3 * N_PTS) return;
  int b = t / (3 * N_PTS);
  int r = t - b * 3 * N_PTS;
  int c = r / N_PTS;
  int n = r - c * N_PTS;
  feat0[((size_t)(b * N_PTS + n)) * 4 + c] = x[t];
}

// ---------------- squared norms per point ----------------
__global__ __launch_bounds__(256) void xnorm_kernel(const float* __restrict__ feat, int lda,
                                                    int C, float* __restrict__ x2) {
  int p = blockIdx.x * 256 + threadIdx.x;
  if (p >= 8192) return;
  const float* r = feat + (size_t)p * lda;
  float s = 0.f;
  for (int c = 0; c < C; c += 4) {
    float4 v = *(const float4*)(r + c);
    s = fmaf(v.x, v.x, s); s = fmaf(v.y, v.y, s);
    s = fmaf(v.z, v.z, s); s = fmaf(v.w, v.w, s);
  }
  x2[p] = s;
}

// ---------------- fused KNN: distances in-register + top-20 selection ----------------
// Block = 4 waves, 16 rows (4 rows/wave). Lane holds cols j*64+lane, j=0..15.
// __launch_bounds__(256, 2): min 2 waves/EU -> VGPR cap 256, so acc[4][16] stays
// register-resident (default heuristic capped at 64 VGPR and spilled acc to scratch:
// R6/R7 showed VGPR_Count 56/64 with 156-167us flat across layers).
__global__ __launch_bounds__(256, 2) void knn_fused(const float* __restrict__ feat, int lda,
                                                    int C4, const float* __restrict__ x2,
                                                    int* __restrict__ idxout) {
  __shared__ float4 xms[1024];          // 16 KB: all candidates' current k-slice
  __shared__ float4 xn_sh[16 * 32];     // 8 KB: this block's 16 query rows (C4<=32)
  int tid = threadIdx.x;
  int warp = tid >> 6, lane = tid & 63;
  int row0 = blockIdx.x * 16;           // 16 rows/block, same batch (16 | 1024)
  int b = row0 >> 10;
  const float* featB = feat + (size_t)b * N_PTS * lda;

  for (int idx = tid; idx < 16 * C4; idx += 256) {
    int r = idx / C4, q = idx - r * C4;
    xn_sh[r * 32 + q] = *(const float4*)(feat + (size_t)(row0 + r) * lda + (q << 2));
  }

  float acc[4][16];
  #pragma unroll
  for (int r = 0; r < 4; ++r)
    #pragma unroll
    for (int j = 0; j < 16; ++j) acc[r][j] = 0.f;

  for (int k4 = 0; k4 < C4; ++k4) {
    #pragma unroll 4
    for (int p = tid; p < 1024; p += 256)
      xms[p] = *(const float4*)(featB + (size_t)p * lda + (k4 << 2));
    __syncthreads();
    float4 xn[4];
    #pragma unroll
    for (int r = 0; r < 4; ++r) xn[r] = xn_sh[(warp * 4 + r) * 32 + k4];
    #pragma unroll
    for (int j = 0; j < 16; ++j) {
      float4 xm = xms[j * 64 + lane];
      #pragma unroll
      for (int r = 0; r < 4; ++r) {
        acc[r][j] = fmaf(xn[r].x, xm.x, acc[r][j]);
        acc[r][j] = fmaf(xn[r].y, xm.y, acc[r][j]);
        acc[r][j] = fmaf(xn[r].z, xm.z, acc[r][j]);
        acc[r][j] = fmaf(xn[r].w, xm.w, acc[r][j]);
      }
    }
    __syncthreads();
  }

  // epilogue: pd = (2*dot - x2n) - x2m (same expression as proven dist_gemm)
  const float* x2b = x2 + b * N_PTS;
  float x2n[4];
  #pragma unroll
  for (int r = 0; r < 4; ++r) x2n[r] = x2[row0 + warp * 4 + r];
  #pragma unroll
  for (int j = 0; j < 16; ++j) {
    float x2cj = x2b[j * 64 + lane];
    #pragma unroll
    for (int r = 0; r < 4; ++r)
      acc[r][j] = (2.f * acc[r][j] - x2n[r]) - x2cj;
  }

  // top-20: argmax-iterate, rounds outer / rows inner (4 butterflies in flight)
  for (int rr = 0; rr < KNN_K; ++rr) {
    float bv[4];
    int bi[4];
    #pragma unroll
    for (int r = 0; r < 4; ++r) { bv[r] = -3.4e38f; bi[r] = 0x7fffffff; }
    #pragma unroll
    for (int j = 0; j < 16; ++j)      // j ascending: strict > keeps smallest col on tie
      #pragma unroll
      for (int r = 0; r < 4; ++r)
        if (acc[r][j] > bv[r]) { bv[r] = acc[r][j]; bi[r] = j * 64 + lane; }
    #pragma unroll
    for (int off = 32; off; off >>= 1)
      #pragma unroll
      for (int r = 0; r < 4; ++r) {
        float ov = __shfl_xor(bv[r], off, 64);
        int oi = __shfl_xor(bi[r], off, 64);
        if (ov > bv[r] || (ov == bv[r] && oi < bi[r])) { bv[r] = ov; bi[r] = oi; }
      }
    #pragma unroll
    for (int r = 0; r < 4; ++r) {
      int jj = bi[r] >> 6, ln = bi[r] & 63;   // wave-uniform
      #pragma unroll
      for (int j = 0; j < 16; ++j)            // compile-time-indexed clear
        acc[r][j] = (ln == lane && jj == j) ? -3.4e38f : acc[r][j];
      if (lane == 0) idxout[(row0 + warp * 4 + r) * KNN_K + rr] = bi[r];
    }
  }
}

// ---------------- build combined weight Wc (fp32): [w1-w2 | w2], K=C rows x 2O cols ----------------
__global__ __launch_bounds__(256) void build_wc(const float* __restrict__ w, int C, int O,
                                                float* __restrict__ wc) {
  int t = blockIdx.x * 256 + threadIdx.x;
  int twoO = 2 * O;
  if (t >= C * twoO) return;
  int c = t / twoO, j = t - c * twoO;
  float v;
  if (j < O) v = w[j * (2 * C) + c] - w[j * (2 * C) + C + c];
  else       v = w[(j - O) * (2 * C) + C + c];
  wc[t] = v;
}

// ---------------- fp32 GEMM (edge layers): C[M,N] = A[M,K](lda) * B[K,N] ----------------
__global__ __launch_bounds__(256) void gemm_kernel(const float* __restrict__ A, int lda,
                                                   const float* __restrict__ Bm,
                                                   float* __restrict__ Cm,
                                                   int M, int N, int K) {
  __shared__ float As[16][64];
  __shared__ float Bs[16][68];
  int tx = threadIdx.x & 15, ty = threadIdx.x >> 4;
  int bn0 = blockIdx.x * 64, bm0 = blockIdx.y * 64;
  float acc[4][4];
  #pragma unroll
  for (int i = 0; i < 4; ++i)
    #pragma unroll
    for (int j = 0; j < 4; ++j) acc[i][j] = 0.f;

  for (int k0 = 0; k0 < K; k0 += 16) {
    {
      int t = threadIdx.x;
      int m = t >> 2, kb = (t & 3) * 4;
      const float* ap = A + (size_t)(bm0 + m) * lda + k0 + kb;
      #pragma unroll
      for (int i = 0; i < 4; ++i) As[kb + i][m] = (k0 + kb + i < K) ? ap[i] : 0.f;
      int r = t >> 4, c4 = (t & 15) * 4;
      float4 bv = make_float4(0.f, 0.f, 0.f, 0.f);
      if (k0 + r < K) bv = *(const float4*)(Bm + (size_t)(k0 + r) * N + bn0 + c4);
      *(float4*)&Bs[r][c4] = bv;
    }
    __syncthreads();
    #pragma unroll
    for (int k = 0; k < 16; ++k) {
      float a0[4];
      #pragma unroll
      for (int i = 0; i < 4; ++i) a0[i] = As[k][ty * 4 + i];
      float4 bv = *(const float4*)&Bs[k][tx * 4];
      float b0[4] = {bv.x, bv.y, bv.z, bv.w};
      #pragma unroll
      for (int i = 0; i < 4; ++i)
        #pragma unroll
        for (int j = 0; j < 4; ++j) acc[i][j] = fmaf(a0[i], b0[j], acc[i][j]);
    }
    __syncthreads();
  }
  #pragma unroll
  for (int i = 0; i < 4; ++i) {
    float4 v = make_float4(acc[i][0], acc[i][1], acc[i][2], acc[i][3]);
    *(float4*)(Cm + (size_t)(bm0 + ty * 4 + i) * N + bn0 + tx * 4) = v;
  }
}

// ---------------- split fp32 -> bf16 hi/lo MFMA GEMM for layer 5, fused reduction ----------------
__device__ inline void split8(const float* __restrict__ p, bf16x8* hv, bf16x8* lv) {
  float4 a0 = *(const float4*)p, a1 = *(const float4*)(p + 4);
  float v[8] = {a0.x, a0.y, a0.z, a0.w, a1.x, a1.y, a1.z, a1.w};
  bf16x8 h, l;
  #pragma unroll
  for (int j = 0; j < 8; ++j) {
    __bf16 hj = (__bf16)v[j];
    h[j] = hj;
    l[j] = (__bf16)(v[j] - (float)hj);
  }
  *hv = h; *lv = l;
}

__global__ __launch_bounds__(256) void gemm_split_red(const float* __restrict__ A, int lda,
                                                      const float* __restrict__ Bt, int ldb,
                                                      float* __restrict__ parts, int K) {
  __shared__ u16 Ah[128 * 64];
  __shared__ u16 Al[128 * 64];
  __shared__ u16 Bh[128 * 64];
  __shared__ u16 Bl[128 * 64];
  int tid = threadIdx.x;
  int wave = tid >> 6, lane = tid & 63;
  int wr = wave >> 1, wc = wave & 1;
  int bn0 = blockIdx.x * 128, bm0 = blockIdx.y * 128;
  int lrow = lane & 15;
  int kgrp = lane >> 4;

  f32x4 acc[4][4];
  #pragma unroll
  for (int i = 0; i < 4; ++i)
    #pragma unroll
    for (int j = 0; j < 4; ++j) acc[i][j] = (f32x4){0.f, 0.f, 0.f, 0.f};

  for (int k0 = 0; k0 < K; k0 += 64) {
    #pragma unroll
    for (int i = 0; i < 4; ++i) {
      int chunk = tid + i * 256;        // 0..1023
      int row = chunk >> 3;             // 0..127
      int cc = (chunk & 7) * 8;         // fp32 col 0,8,..,56
      int byte = row * 128 + ((cc * 2) ^ ((row & 7) << 4));
      bf16x8 h, l;
      split8(A + (size_t)(bm0 + row) * lda + k0 + cc, &h, &l);
      *(bf16x8*)((char*)Ah + byte) = h;
      *(bf16x8*)((char*)Al + byte) = l;
      split8(Bt + (size_t)(bn0 + row) * ldb + k0 + cc, &h, &l);
      *(bf16x8*)((char*)Bh + byte) = h;
      *(bf16x8*)((char*)Bl + byte) = l;
    }
    __syncthreads();
    #pragma unroll
    for (int kk = 0; kk < 64; kk += 32) {
      int kb = (kk + kgrp * 8) * 2;
      bf16x8 afh[4], afl[4], bfh[4], bfl[4];
      #pragma unroll
      for (int f = 0; f < 4; ++f) {
        int arow = wr * 64 + f * 16 + lrow;
        int abyte = arow * 128 + (kb ^ ((arow & 7) << 4));
        afh[f] = *(const bf16x8*)((const char*)Ah + abyte);
        afl[f] = *(const bf16x8*)((const char*)Al + abyte);
        int brow = wc * 64 + f * 16 + lrow;
        int bbyte = brow * 128 + (kb ^ ((brow & 7) << 4));
        bfh[f] = *(const bf16x8*)((const char*)Bh + bbyte);
        bfl[f] = *(const bf16x8*)((const char*)Bl + bbyte);
      }
      #pragma unroll
      for (int fm = 0; fm < 4; ++fm)
        #pragma unroll
        for (int fn = 0; fn < 4; ++fn) {
          acc[fm][fn] = __builtin_amdgcn_mfma_f32_16x16x32_bf16(afh[fm], bfh[fn], acc[fm][fn], 0, 0, 0);
          acc[fm][fn] = __builtin_amdgcn_mfma_f32_16x16x32_bf16(afl[fm], bfh[fn], acc[fm][fn], 0, 0, 0);
          acc[fm][fn] = __builtin_amdgcn_mfma_f32_16x16x32_bf16(afh[fm], bfl[fn], acc[fm][fn], 0, 0, 0);
        }
    }
    __syncthreads();
  }

  // fused per-tile reduction over the 128 rows
  float* scratch = (float*)Ah;
  int contrib = wr * 4 + kgrp;
  #pragma unroll
  for (int fn = 0; fn < 4; ++fn) {
    float mx = -3.4e38f, mn = 3.4e38f, s1 = 0.f, s2 = 0.f;
    #pragma unroll
    for (int fm = 0; fm < 4; ++fm)
      #pragma unroll
      for (int r = 0; r < 4; ++r) {
        float v = acc[fm][fn][r];
        mx = fmaxf(mx, v); mn = fminf(mn, v);
        s1 += v; s2 = fmaf(v, v, s2);
      }
    int col = wc * 64 + fn * 16 + lrow;
    float* sp = scratch + (contrib * 128 + col) * 4;
    sp[0] = mx; sp[1] = mn; sp[2] = s1; sp[3] = s2;
  }
  __syncthreads();
  if (tid < 128) {
    float mx = -3.4e38f, mn = 3.4e38f, s1 = 0.f, s2 = 0.f;
    #pragma unroll
    for (int c2 = 0; c2 < 8; ++c2) {
      const float* sp = scratch + (c2 * 128 + tid) * 4;
      mx = fmaxf(mx, sp[0]); mn = fminf(mn, sp[1]);
      s1 += sp[2]; s2 += sp[3];
    }
    size_t o = (size_t)blockIdx.y * 1024 + bn0 + tid;
    parts[o] = mx;
    parts[65536 + o] = mn;
    parts[131072 + o] = s1;
    parts[196608 + o] = s2;
  }
}

// ---------------- edge aggregation: h = a + y[idx]; max/min over k + channel sums ----------------
__global__ __launch_bounds__(256) void aggregate_kernel(const float* __restrict__ ay,
                                                        const int* __restrict__ idxb, int O,
                                                        float* __restrict__ mx,
                                                        float* __restrict__ mn,
                                                        float* __restrict__ sumsbin) {
  __shared__ float ls[2][256];
  for (int i = threadIdx.x; i < 512; i += 256) ((float*)ls)[i] = 0.f;
  __syncthreads();

  int warp = threadIdx.x >> 6, lane = threadIdx.x & 63;
  int pt = blockIdx.x * 4 + warp;   // 0..8191
  int b = pt >> 10;
  int twoO = 2 * O;
  int U = O >> 6;
  const float* ayrow = ay + (size_t)pt * twoO;

  float av[4], s1[4], s2[4], vmx[4], vmn[4];
  for (int u = 0; u < U; ++u) {
    av[u] = ayrow[u * 64 + lane];
    s1[u] = 0.f; s2[u] = 0.f; vmx[u] = -3.4e38f; vmn[u] = 3.4e38f;
  }
  const int* ip = idxb + pt * KNN_K;
  for (int k = 0; k < KNN_K; ++k) {
    int j = ip[k];
    const float* yrow = ay + (size_t)(b * N_PTS + j) * twoO + O;
    for (int u = 0; u < U; ++u) {
      float v = av[u] + yrow[u * 64 + lane];
      s1[u] += v; s2[u] = fmaf(v, v, s2[u]);
      vmx[u] = fmaxf(vmx[u], v); vmn[u] = fminf(vmn[u], v);
    }
  }
  for (int u = 0; u < U; ++u) {
    int o = u * 64 + lane;
    mx[(size_t)pt * O + o] = vmx[u];
    mn[(size_t)pt * O + o] = vmn[u];
    atomicAdd(&ls[0][o], s1[u]);
    atomicAdd(&ls[1][o], s2[u]);
  }
  __syncthreads();
  int bin = blockIdx.x & 63;
  float* gb = sumsbin + (size_t)bin * 512;
  for (int o = threadIdx.x; o < O; o += 256) {
    atomicAdd(&gb[o], ls[0][o]);
    atomicAdd(&gb[256 + o], ls[1][o]);
  }
}

__global__ __launch_bounds__(256) void reduce_bins(const float* __restrict__ sumsbin,
                                                   float* __restrict__ sums, int O) {
  int o = threadIdx.x;
  if (o >= O) return;
  float a = 0.f, c = 0.f;
  for (int bin = 0; bin < 64; ++bin) {
    a += sumsbin[bin * 512 + o];
    c += sumsbin[bin * 512 + 256 + o];
  }
  sums[o] = a;
  sums[256 + o] = c;
}

// ---------------- finalize edge layer: BN + relu on (max or min depending on sign) ----------------
__global__ __launch_bounds__(256) void finalize_edge(const float* __restrict__ mx,
                                                     const float* __restrict__ mn,
                                                     const float* __restrict__ sums,
                                                     const float* __restrict__ g,
                                                     const float* __restrict__ beta,
                                                     int oshift,
                                                     float* __restrict__ outseg,
                                                     float cnt_inv) {
  int tid = blockIdx.x * 256 + threadIdx.x;
  int pt = tid >> oshift;
  int o = tid & ((1 << oshift) - 1);
  float s1 = sums[o], s2 = sums[256 + o];
  float mean = s1 * cnt_inv;
  float var = s2 * cnt_inv - mean * mean;
  float rstd = rsqrtf(var + BN_EPS);
  float sc = g[o] * rstd;
  float sel = (sc >= 0.f) ? mx[tid] : mn[tid];
  float v = (sel - mean) * sc + beta[o];
  outseg[(size_t)pt * CAT_C + o] = fmaxf(v, 0.f);
}

// ---------------- layer 5 finalize from tile partials ----------------
__global__ __launch_bounds__(256) void finalize5_fused(const float* __restrict__ parts,
                                                       const float* __restrict__ g,
                                                       const float* __restrict__ beta,
                                                       float* __restrict__ out) {
  int tid = blockIdx.x * 256 + threadIdx.x;   // 0..8191
  int b = tid >> 10, o = tid & 1023;
  const float* pmx = parts;
  const float* pmn = parts + 65536;
  const float* ps1 = parts + 131072;
  const float* ps2 = parts + 196608;
  float s1 = 0.f, s2 = 0.f;
  for (int t = 0; t < 64; ++t) { s1 += ps1[t * 1024 + o]; s2 += ps2[t * 1024 + o]; }
  float mx = -3.4e38f, mn = 3.4e38f;
  #pragma unroll
  for (int t = 0; t < 8; ++t) {
    mx = fmaxf(mx, pmx[(b * 8 + t) * 1024 + o]);
    mn = fminf(mn, pmn[(b * 8 + t) * 1024 + o]);
  }
  float mean = s1 * (1.0f / 8192.0f);
  float var = s2 * (1.0f / 8192.0f) - mean * mean;
  float rstd = rsqrtf(var + BN_EPS);
  float sc = g[o] * rstd;
  float sel = (sc >= 0.f) ? mx : mn;
  float v = (sel - mean) * sc + beta[o];
  out[tid] = fmaxf(v, 0.f);
}

extern "C" void kernel_launch(void* const* d_in, const int* in_sizes, int n_in,
                              void* d_out, int out_size, void* d_ws, size_t ws_size,
                              hipStream_t stream) {
  const float* x = (const float*)d_in[0];
  const float* w[5]  = {(const float*)d_in[1], (const float*)d_in[4], (const float*)d_in[7],
                        (const float*)d_in[10], (const float*)d_in[13]};
  const float* gg[5] = {(const float*)d_in[2], (const float*)d_in[5], (const float*)d_in[8],
                        (const float*)d_in[11], (const float*)d_in[14]};
  const float* bb[5] = {(const float*)d_in[3], (const float*)d_in[6], (const float*)d_in[9],
                        (const float*)d_in[12], (const float*)d_in[15]};
  float* out = (float*)d_out;

  float* W = (float*)d_ws;
  size_t off = 0;
  float* feat0   = W + off; off += (size_t)B_SZ * N_PTS * 4;   // stride-4 padded
  float* catbuf  = W + off; off += (size_t)8192 * CAT_C;
  int*   idxbuf  = (int*)(W + off); off += (size_t)8192 * KNN_K;
  float* aybuf   = W + off; off += (size_t)8192 * 1024;
  float* mxbuf   = W + off; off += (size_t)8192 * 256;
  float* mnbuf   = W + off; off += (size_t)8192 * 256;
  float* wcbuf   = W + off; off += (size_t)512 * 1024;
  float* sumsbin = W + off; off += (size_t)64 * 512;
  float* sums    = W + off; off += 512;
  float* parts   = W + off; off += (size_t)4 * 64 * 1024;  // L5 tile partials (mx,mn,s1,s2)
  float* x2buf   = W + off; off += 8192;

  hipMemsetAsync(feat0, 0, (size_t)B_SZ * N_PTS * 4 * sizeof(float), stream);
  transpose_x<<<(B_SZ * 3 * N_PTS + 255) / 256, 256, 0, stream>>>(x, feat0);

  const int Cs[4] = {4, 64, 64, 128};   // layer-0 padded to 4 (pad=0, values unchanged)
  const int Ks[4] = {3, 64, 64, 128};   // true K for the edge GEMM
  const int Os[4] = {64, 64, 128, 256};
  const int osh[4] = {6, 6, 7, 8};
  const int segin[4] = {0, 0, 64, 128};
  const int segout[4] = {0, 64, 128, 256};

  for (int l = 0; l < 4; ++l) {
    int C = Cs[l], O = Os[l], twoO = 2 * O;
    const float* featin = (l == 0) ? feat0 : (catbuf + segin[l]);
    int lda = (l == 0) ? 4 : CAT_C;

    xnorm_kernel<<<32, 256, 0, stream>>>(featin, lda, C, x2buf);
    knn_fused<<<512, 256, 0, stream>>>(featin, lda, C / 4, x2buf, idxbuf);

    build_wc<<<(Ks[l] * twoO + 255) / 256, 256, 0, stream>>>(w[l], Ks[l], O, wcbuf);
    gemm_kernel<<<dim3(twoO / 64, 8192 / 64), 256, 0, stream>>>(featin, lda, wcbuf, aybuf,
                                                                8192, twoO, Ks[l]);
    hipMemsetAsync(sumsbin, 0, (size_t)64 * 512 * sizeof(float), stream);
    aggregate_kernel<<<2048, 256, 0, stream>>>(aybuf, idxbuf, O, mxbuf, mnbuf, sumsbin);
    reduce_bins<<<1, 256, 0, stream>>>(sumsbin, sums, O);
    finalize_edge<<<(8192 * O) / 256, 256, 0, stream>>>(mxbuf, mnbuf, sums, gg[l], bb[l],
                                                        osh[l], catbuf + segout[l],
                                                        1.0f / (8192.0f * KNN_K));
  }

  // layer 5: h5 = cat * w5^T via split-bf16 MFMA with fused per-tile reduction
  gemm_split_red<<<dim3(1024 / 128, 8192 / 128), 256, 0, stream>>>(catbuf, CAT_C, w[4], 512,
                                                                   parts, 512);
  finalize5_fused<<<8192 / 256, 256, 0, stream>>>(parts, gg[4], bb[4], out);
}

// Round 9
// 607.050 us; speedup vs baseline: 1.2232x; 1.2232x over previous
//
#include <hip/hip_runtime.h>
#include <cstddef>

#define B_SZ 8
#define N_PTS 1024
#define KNN_K 20
#define CAT_C 512
#define BN_EPS 1e-5f

typedef unsigned short u16;
typedef unsigned int u32;
typedef __bf16 bf16x8 __attribute__((ext_vector_type(8)));
typedef float f32x4 __attribute__((ext_vector_type(4)));

// ---------------- transpose x (B,3,N) -> feat0 (B,N,4) (col 3 pre-zeroed) ----------------
__global__ __launch_bounds__(256) void transpose_x(const float* __restrict__ x,
                                                   float* __restrict__ feat0) {
  int t = blockIdx.x * 256 + threadIdx.x;
  if (t >= B_SZ * 3 * N_PTS) return;
  int b = t / (3 * N_PTS);
  int r = t - b * 3 * N_PTS;
  int c = r / N_PTS;
  int n = r - c * N_PTS;
  feat0[((size_t)(b * N_PTS + n)) * 4 + c] = x[t];
}

// ---------------- squared norms per point ----------------
__global__ __launch_bounds__(256) void xnorm_kernel(const float* __restrict__ feat, int lda,
                                                    int C, float* __restrict__ x2) {
  int p = blockIdx.x * 256 + threadIdx.x;
  if (p >= 8192) return;
  const float* r = feat + (size_t)p * lda;
  float s = 0.f;
  for (int c = 0; c < C; c += 4) {
    float4 v = *(const float4*)(r + c);
    s = fmaf(v.x, v.x, s); s = fmaf(v.y, v.y, s);
    s = fmaf(v.z, v.z, s); s = fmaf(v.w, v.w, s);
  }
  x2[p] = s;
}

// ---------------- pack candidates: feat (b,p,4k4..) -> pack[(b*C4+k4)*1024+p] (float4) ----
// Makes knn staging loads perfectly coalesced (consecutive p -> consecutive 16B).
__global__ __launch_bounds__(256) void pack_kernel(const float* __restrict__ feat, int lda,
                                                   int C4, float4* __restrict__ packb) {
  int t = blockIdx.x * 256 + threadIdx.x;
  if (t >= 8192 * C4) return;
  int p = t & 1023;
  int bk = t >> 10;
  int k4 = bk % C4, b = bk / C4;
  packb[t] = *(const float4*)(feat + (size_t)(b * 1024 + p) * lda + (k4 << 2));
}

// ---------------- fused KNN: distances in-register + top-20 selection ----------------
// 512 threads = 8 waves; ONE row per wave -> acc[16] = 16 VGPRs, total demand ~50
// (fits the backend's default 64-VGPR occupancy budget; R6-R8's acc[4][16] demanded
// 64+ and was spilled to scratch: VGPR_Count 56/60/64 with flat 156-167us).
// Lane holds cols j*64+lane. Same distance expr / k-order / tie-break as proven rounds.
__global__ __launch_bounds__(512) void knn_fused(const float* __restrict__ feat, int lda,
                                                 int C4, const float4* __restrict__ pack,
                                                 const float* __restrict__ x2,
                                                 int* __restrict__ idxout) {
  __shared__ float4 xms[1024];        // 16 KB: all candidates' current k-slice
  __shared__ float4 xn_sh[8 * 32];    // 4 KB: the block's 8 query rows (C4<=32)
  int tid = threadIdx.x;
  int w = tid >> 6, lane = tid & 63;
  int row0 = blockIdx.x * 8;          // 8 rows/block, same batch (8 | 1024)
  int b = row0 >> 10;
  int row = row0 + w;
  const float4* packB = pack + (size_t)b * C4 * 1024;

  if (tid < 8 * C4) {                 // 8*C4 <= 256 <= 512
    int r = tid / C4, q = tid - r * C4;
    xn_sh[r * 32 + q] = *(const float4*)(feat + (size_t)(row0 + r) * lda + (q << 2));
  }

  float acc[16];
  #pragma unroll
  for (int j = 0; j < 16; ++j) acc[j] = 0.f;

  for (int k4 = 0; k4 < C4; ++k4) {
    xms[tid] = packB[k4 * 1024 + tid];
    xms[tid + 512] = packB[k4 * 1024 + tid + 512];
    __syncthreads();
    float4 xn = xn_sh[w * 32 + k4];   // wave-uniform -> broadcast
    #pragma unroll
    for (int j = 0; j < 16; ++j) {
      float4 xm = xms[j * 64 + lane];
      acc[j] = fmaf(xn.x, xm.x, acc[j]);
      acc[j] = fmaf(xn.y, xm.y, acc[j]);
      acc[j] = fmaf(xn.z, xm.z, acc[j]);
      acc[j] = fmaf(xn.w, xm.w, acc[j]);
    }
    __syncthreads();
  }

  // epilogue: pd = (2*dot - x2n) - x2m (identical expression to proven kernels)
  const float* x2b = x2 + b * N_PTS;
  float x2n = x2[row];
  #pragma unroll
  for (int j = 0; j < 16; ++j)
    acc[j] = (2.f * acc[j] - x2n) - x2b[j * 64 + lane];

  // top-20: argmax-iterate (proven semantics: strict > keeps smallest col in-lane,
  // butterfly tie-break oi<bi picks smallest global col)
  for (int rr = 0; rr < KNN_K; ++rr) {
    float bv = -3.4e38f;
    int bi = 0x7fffffff;
    #pragma unroll
    for (int j = 0; j < 16; ++j)
      if (acc[j] > bv) { bv = acc[j]; bi = j * 64 + lane; }
    #pragma unroll
    for (int off = 32; off; off >>= 1) {
      float ov = __shfl_xor(bv, off, 64);
      int oi = __shfl_xor(bi, off, 64);
      if (ov > bv || (ov == bv && oi < bi)) { bv = ov; bi = oi; }
    }
    int jj = bi >> 6, ln = bi & 63;   // wave-uniform
    #pragma unroll
    for (int j = 0; j < 16; ++j)      // compile-time-indexed clear
      acc[j] = (ln == lane && jj == j) ? -3.4e38f : acc[j];
    if (lane == 0) idxout[row * KNN_K + rr] = bi;
  }
}

// ---------------- build combined weight Wc (fp32): [w1-w2 | w2], K=C rows x 2O cols ----------------
__global__ __launch_bounds__(256) void build_wc(const float* __restrict__ w, int C, int O,
                                                float* __restrict__ wc) {
  int t = blockIdx.x * 256 + threadIdx.x;
  int twoO = 2 * O;
  if (t >= C * twoO) return;
  int c = t / twoO, j = t - c * twoO;
  float v;
  if (j < O) v = w[j * (2 * C) + c] - w[j * (2 * C) + C + c];
  else       v = w[(j - O) * (2 * C) + C + c];
  wc[t] = v;
}

// ---------------- fp32 GEMM (edge layers): C[M,N] = A[M,K](lda) * B[K,N] ----------------
__global__ __launch_bounds__(256) void gemm_kernel(const float* __restrict__ A, int lda,
                                                   const float* __restrict__ Bm,
                                                   float* __restrict__ Cm,
                                                   int M, int N, int K) {
  __shared__ float As[16][64];
  __shared__ float Bs[16][68];
  int tx = threadIdx.x & 15, ty = threadIdx.x >> 4;
  int bn0 = blockIdx.x * 64, bm0 = blockIdx.y * 64;
  float acc[4][4];
  #pragma unroll
  for (int i = 0; i < 4; ++i)
    #pragma unroll
    for (int j = 0; j < 4; ++j) acc[i][j] = 0.f;

  for (int k0 = 0; k0 < K; k0 += 16) {
    {
      int t = threadIdx.x;
      int m = t >> 2, kb = (t & 3) * 4;
      const float* ap = A + (size_t)(bm0 + m) * lda + k0 + kb;
      #pragma unroll
      for (int i = 0; i < 4; ++i) As[kb + i][m] = (k0 + kb + i < K) ? ap[i] : 0.f;
      int r = t >> 4, c4 = (t & 15) * 4;
      float4 bv = make_float4(0.f, 0.f, 0.f, 0.f);
      if (k0 + r < K) bv = *(const float4*)(Bm + (size_t)(k0 + r) * N + bn0 + c4);
      *(float4*)&Bs[r][c4] = bv;
    }
    __syncthreads();
    #pragma unroll
    for (int k = 0; k < 16; ++k) {
      float a0[4];
      #pragma unroll
      for (int i = 0; i < 4; ++i) a0[i] = As[k][ty * 4 + i];
      float4 bv = *(const float4*)&Bs[k][tx * 4];
      float b0[4] = {bv.x, bv.y, bv.z, bv.w};
      #pragma unroll
      for (int i = 0; i < 4; ++i)
        #pragma unroll
        for (int j = 0; j < 4; ++j) acc[i][j] = fmaf(a0[i], b0[j], acc[i][j]);
    }
    __syncthreads();
  }
  #pragma unroll
  for (int i = 0; i < 4; ++i) {
    float4 v = make_float4(acc[i][0], acc[i][1], acc[i][2], acc[i][3]);
    *(float4*)(Cm + (size_t)(bm0 + ty * 4 + i) * N + bn0 + tx * 4) = v;
  }
}

// ---------------- split fp32 -> bf16 hi/lo MFMA GEMM for layer 5, fused reduction ----------------
__device__ inline void split8(const float* __restrict__ p, bf16x8* hv, bf16x8* lv) {
  float4 a0 = *(const float4*)p, a1 = *(const float4*)(p + 4);
  float v[8] = {a0.x, a0.y, a0.z, a0.w, a1.x, a1.y, a1.z, a1.w};
  bf16x8 h, l;
  #pragma unroll
  for (int j = 0; j < 8; ++j) {
    __bf16 hj = (__bf16)v[j];
    h[j] = hj;
    l[j] = (__bf16)(v[j] - (float)hj);
  }
  *hv = h; *lv = l;
}

__global__ __launch_bounds__(256) void gemm_split_red(const float* __restrict__ A, int lda,
                                                      const float* __restrict__ Bt, int ldb,
                                                      float* __restrict__ parts, int K) {
  __shared__ u16 Ah[128 * 64];
  __shared__ u16 Al[128 * 64];
  __shared__ u16 Bh[128 * 64];
  __shared__ u16 Bl[128 * 64];
  int tid = threadIdx.x;
  int wave = tid >> 6, lane = tid & 63;
  int wr = wave >> 1, wc = wave & 1;
  int bn0 = blockIdx.x * 128, bm0 = blockIdx.y * 128;
  int lrow = lane & 15;
  int kgrp = lane >> 4;

  f32x4 acc[4][4];
  #pragma unroll
  for (int i = 0; i < 4; ++i)
    #pragma unroll
    for (int j = 0; j < 4; ++j) acc[i][j] = (f32x4){0.f, 0.f, 0.f, 0.f};

  for (int k0 = 0; k0 < K; k0 += 64) {
    #pragma unroll
    for (int i = 0; i < 4; ++i) {
      int chunk = tid + i * 256;        // 0..1023
      int row = chunk >> 3;             // 0..127
      int cc = (chunk & 7) * 8;         // fp32 col 0,8,..,56
      int byte = row * 128 + ((cc * 2) ^ ((row & 7) << 4));
      bf16x8 h, l;
      split8(A + (size_t)(bm0 + row) * lda + k0 + cc, &h, &l);
      *(bf16x8*)((char*)Ah + byte) = h;
      *(bf16x8*)((char*)Al + byte) = l;
      split8(Bt + (size_t)(bn0 + row) * ldb + k0 + cc, &h, &l);
      *(bf16x8*)((char*)Bh + byte) = h;
      *(bf16x8*)((char*)Bl + byte) = l;
    }
    __syncthreads();
    #pragma unroll
    for (int kk = 0; kk < 64; kk += 32) {
      int kb = (kk + kgrp * 8) * 2;
      bf16x8 afh[4], afl[4], bfh[4], bfl[4];
      #pragma unroll
      for (int f = 0; f < 4; ++f) {
        int arow = wr * 64 + f * 16 + lrow;
        int abyte = arow * 128 + (kb ^ ((arow & 7) << 4));
        afh[f] = *(const bf16x8*)((const char*)Ah + abyte);
        afl[f] = *(const bf16x8*)((const char*)Al + abyte);
        int brow = wc * 64 + f * 16 + lrow;
        int bbyte = brow * 128 + (kb ^ ((brow & 7) << 4));
        bfh[f] = *(const bf16x8*)((const char*)Bh + bbyte);
        bfl[f] = *(const bf16x8*)((const char*)Bl + bbyte);
      }
      #pragma unroll
      for (int fm = 0; fm < 4; ++fm)
        #pragma unroll
        for (int fn = 0; fn < 4; ++fn) {
          acc[fm][fn] = __builtin_amdgcn_mfma_f32_16x16x32_bf16(afh[fm], bfh[fn], acc[fm][fn], 0, 0, 0);
          acc[fm][fn] = __builtin_amdgcn_mfma_f32_16x16x32_bf16(afl[fm], bfh[fn], acc[fm][fn], 0, 0, 0);
          acc[fm][fn] = __builtin_amdgcn_mfma_f32_16x16x32_bf16(afh[fm], bfl[fn], acc[fm][fn], 0, 0, 0);
        }
    }
    __syncthreads();
  }

  // fused per-tile reduction over the 128 rows
  float* scratch = (float*)Ah;
  int contrib = wr * 4 + kgrp;
  #pragma unroll
  for (int fn = 0; fn < 4; ++fn) {
    float mx = -3.4e38f, mn = 3.4e38f, s1 = 0.f, s2 = 0.f;
    #pragma unroll
    for (int fm = 0; fm < 4; ++fm)
      #pragma unroll
      for (int r = 0; r < 4; ++r) {
        float v = acc[fm][fn][r];
        mx = fmaxf(mx, v); mn = fminf(mn, v);
        s1 += v; s2 = fmaf(v, v, s2);
      }
    int col = wc * 64 + fn * 16 + lrow;
    float* sp = scratch + (contrib * 128 + col) * 4;
    sp[0] = mx; sp[1] = mn; sp[2] = s1; sp[3] = s2;
  }
  __syncthreads();
  if (tid < 128) {
    float mx = -3.4e38f, mn = 3.4e38f, s1 = 0.f, s2 = 0.f;
    #pragma unroll
    for (int c2 = 0; c2 < 8; ++c2) {
      const float* sp = scratch + (c2 * 128 + tid) * 4;
      mx = fmaxf(mx, sp[0]); mn = fminf(mn, sp[1]);
      s1 += sp[2]; s2 += sp[3];
    }
    size_t o = (size_t)blockIdx.y * 1024 + bn0 + tid;
    parts[o] = mx;
    parts[65536 + o] = mn;
    parts[131072 + o] = s1;
    parts[196608 + o] = s2;
  }
}

// ---------------- edge aggregation: h = a + y[idx]; max/min over k + channel sums ----------------
__global__ __launch_bounds__(256) void aggregate_kernel(const float* __restrict__ ay,
                                                        const int* __restrict__ idxb, int O,
                                                        float* __restrict__ mx,
                                                        float* __restrict__ mn,
                                                        float* __restrict__ sumsbin) {
  __shared__ float ls[2][256];
  for (int i = threadIdx.x; i < 512; i += 256) ((float*)ls)[i] = 0.f;
  __syncthreads();

  int warp = threadIdx.x >> 6, lane = threadIdx.x & 63;
  int pt = blockIdx.x * 4 + warp;   // 0..8191
  int b = pt >> 10;
  int twoO = 2 * O;
  int U = O >> 6;
  const float* ayrow = ay + (size_t)pt * twoO;

  float av[4], s1[4], s2[4], vmx[4], vmn[4];
  for (int u = 0; u < U; ++u) {
    av[u] = ayrow[u * 64 + lane];
    s1[u] = 0.f; s2[u] = 0.f; vmx[u] = -3.4e38f; vmn[u] = 3.4e38f;
  }
  const int* ip = idxb + pt * KNN_K;
  for (int k = 0; k < KNN_K; ++k) {
    int j = ip[k];
    const float* yrow = ay + (size_t)(b * N_PTS + j) * twoO + O;
    for (int u = 0; u < U; ++u) {
      float v = av[u] + yrow[u * 64 + lane];
      s1[u] += v; s2[u] = fmaf(v, v, s2[u]);
      vmx[u] = fmaxf(vmx[u], v); vmn[u] = fminf(vmn[u], v);
    }
  }
  for (int u = 0; u < U; ++u) {
    int o = u * 64 + lane;
    mx[(size_t)pt * O + o] = vmx[u];
    mn[(size_t)pt * O + o] = vmn[u];
    atomicAdd(&ls[0][o], s1[u]);
    atomicAdd(&ls[1][o], s2[u]);
  }
  __syncthreads();
  int bin = blockIdx.x & 63;
  float* gb = sumsbin + (size_t)bin * 512;
  for (int o = threadIdx.x; o < O; o += 256) {
    atomicAdd(&gb[o], ls[0][o]);
    atomicAdd(&gb[256 + o], ls[1][o]);
  }
}

__global__ __launch_bounds__(256) void reduce_bins(const float* __restrict__ sumsbin,
                                                   float* __restrict__ sums, int O) {
  int o = threadIdx.x;
  if (o >= O) return;
  float a = 0.f, c = 0.f;
  for (int bin = 0; bin < 64; ++bin) {
    a += sumsbin[bin * 512 + o];
    c += sumsbin[bin * 512 + 256 + o];
  }
  sums[o] = a;
  sums[256 + o] = c;
}

// ---------------- finalize edge layer: BN + relu on (max or min depending on sign) ----------------
__global__ __launch_bounds__(256) void finalize_edge(const float* __restrict__ mx,
                                                     const float* __restrict__ mn,
                                                     const float* __restrict__ sums,
                                                     const float* __restrict__ g,
                                                     const float* __restrict__ beta,
                                                     int oshift,
                                                     float* __restrict__ outseg,
                                                     float cnt_inv) {
  int tid = blockIdx.x * 256 + threadIdx.x;
  int pt = tid >> oshift;
  int o = tid & ((1 << oshift) - 1);
  float s1 = sums[o], s2 = sums[256 + o];
  float mean = s1 * cnt_inv;
  float var = s2 * cnt_inv - mean * mean;
  float rstd = rsqrtf(var + BN_EPS);
  float sc = g[o] * rstd;
  float sel = (sc >= 0.f) ? mx[tid] : mn[tid];
  float v = (sel - mean) * sc + beta[o];
  outseg[(size_t)pt * CAT_C + o] = fmaxf(v, 0.f);
}

// ---------------- layer 5 finalize from tile partials ----------------
__global__ __launch_bounds__(256) void finalize5_fused(const float* __restrict__ parts,
                                                       const float* __restrict__ g,
                                                       const float* __restrict__ beta,
                                                       float* __restrict__ out) {
  int tid = blockIdx.x * 256 + threadIdx.x;   // 0..8191
  int b = tid >> 10, o = tid & 1023;
  const float* pmx = parts;
  const float* pmn = parts + 65536;
  const float* ps1 = parts + 131072;
  const float* ps2 = parts + 196608;
  float s1 = 0.f, s2 = 0.f;
  for (int t = 0; t < 64; ++t) { s1 += ps1[t * 1024 + o]; s2 += ps2[t * 1024 + o]; }
  float mx = -3.4e38f, mn = 3.4e38f;
  #pragma unroll
  for (int t = 0; t < 8; ++t) {
    mx = fmaxf(mx, pmx[(b * 8 + t) * 1024 + o]);
    mn = fminf(mn, pmn[(b * 8 + t) * 1024 + o]);
  }
  float mean = s1 * (1.0f / 8192.0f);
  float var = s2 * (1.0f / 8192.0f) - mean * mean;
  float rstd = rsqrtf(var + BN_EPS);
  float sc = g[o] * rstd;
  float sel = (sc >= 0.f) ? mx : mn;
  float v = (sel - mean) * sc + beta[o];
  out[tid] = fmaxf(v, 0.f);
}

extern "C" void kernel_launch(void* const* d_in, const int* in_sizes, int n_in,
                              void* d_out, int out_size, void* d_ws, size_t ws_size,
                              hipStream_t stream) {
  const float* x = (const float*)d_in[0];
  const float* w[5]  = {(const float*)d_in[1], (const float*)d_in[4], (const float*)d_in[7],
                        (const float*)d_in[10], (const float*)d_in[13]};
  const float* gg[5] = {(const float*)d_in[2], (const float*)d_in[5], (const float*)d_in[8],
                        (const float*)d_in[11], (const float*)d_in[14]};
  const float* bb[5] = {(const float*)d_in[3], (const float*)d_in[6], (const float*)d_in[9],
                        (const float*)d_in[12], (const float*)d_in[15]};
  float* out = (float*)d_out;

  float* W = (float*)d_ws;
  size_t off = 0;
  float* feat0   = W + off; off += (size_t)B_SZ * N_PTS * 4;   // stride-4 padded
  float* catbuf  = W + off; off += (size_t)8192 * CAT_C;
  int*   idxbuf  = (int*)(W + off); off += (size_t)8192 * KNN_K;
  float* aybuf   = W + off; off += (size_t)8192 * 1024;
  float* mxbuf   = W + off; off += (size_t)8192 * 256;
  float* mnbuf   = W + off; off += (size_t)8192 * 256;
  float* wcbuf   = W + off; off += (size_t)512 * 1024;
  float* sumsbin = W + off; off += (size_t)64 * 512;
  float* sums    = W + off; off += 512;
  float* parts   = W + off; off += (size_t)4 * 64 * 1024;  // L5 tile partials (mx,mn,s1,s2)
  float* x2buf   = W + off; off += 8192;
  float4* packbuf = (float4*)(W + off); off += (size_t)8192 * 32 * 4;  // [b][k4][1024] f4, 4MB

  hipMemsetAsync(feat0, 0, (size_t)B_SZ * N_PTS * 4 * sizeof(float), stream);
  transpose_x<<<(B_SZ * 3 * N_PTS + 255) / 256, 256, 0, stream>>>(x, feat0);

  const int Cs[4] = {4, 64, 64, 128};   // layer-0 padded to 4 (pad=0, values unchanged)
  const int Ks[4] = {3, 64, 64, 128};   // true K for the edge GEMM
  const int Os[4] = {64, 64, 128, 256};
  const int osh[4] = {6, 6, 7, 8};
  const int segin[4] = {0, 0, 64, 128};
  const int segout[4] = {0, 64, 128, 256};

  for (int l = 0; l < 4; ++l) {
    int C = Cs[l], O = Os[l], twoO = 2 * O;
    const float* featin = (l == 0) ? feat0 : (catbuf + segin[l]);
    int lda = (l == 0) ? 4 : CAT_C;
    int C4 = C / 4;

    xnorm_kernel<<<32, 256, 0, stream>>>(featin, lda, C, x2buf);
    pack_kernel<<<(8192 * C4 + 255) / 256, 256, 0, stream>>>(featin, lda, C4, packbuf);
    knn_fused<<<1024, 512, 0, stream>>>(featin, lda, C4, packbuf, x2buf, idxbuf);

    build_wc<<<(Ks[l] * twoO + 255) / 256, 256, 0, stream>>>(w[l], Ks[l], O, wcbuf);
    gemm_kernel<<<dim3(twoO / 64, 8192 / 64), 256, 0, stream>>>(featin, lda, wcbuf, aybuf,
                                                                8192, twoO, Ks[l]);
    hipMemsetAsync(sumsbin, 0, (size_t)64 * 512 * sizeof(float), stream);
    aggregate_kernel<<<2048, 256, 0, stream>>>(aybuf, idxbuf, O, mxbuf, mnbuf, sumsbin);
    reduce_bins<<<1, 256, 0, stream>>>(sumsbin, sums, O);
    finalize_edge<<<(8192 * O) / 256, 256, 0, stream>>>(mxbuf, mnbuf, sums, gg[l], bb[l],
                                                        osh[l], catbuf + segout[l],
                                                        1.0f / (8192.0f * KNN_K));
  }

  // layer 5: h5 = cat * w5^T via split-bf16 MFMA with fused per-tile reduction
  gemm_split_red<<<dim3(1024 / 128, 8192 / 128), 256, 0, stream>>>(catbuf, CAT_C, w[4], 512,
                                                                   parts, 512);
  finalize5_fused<<<8192 / 256, 256, 0, stream>>>(parts, gg[4], bb[4], out);
}

// Round 10
// 590.885 us; speedup vs baseline: 1.2567x; 1.0274x over previous
//
#include <hip/hip_runtime.h>
#include <cstddef>

#define B_SZ 8
#define N_PTS 1024
#define KNN_K 20
#define CAT_C 512
#define BN_EPS 1e-5f

typedef unsigned short u16;
typedef unsigned int u32;
typedef __bf16 bf16x8 __attribute__((ext_vector_type(8)));
typedef float f32x4 __attribute__((ext_vector_type(4)));

// ---------------- transpose x (B,3,N) -> feat0 (B,N,4) (col 3 pre-zeroed) ----------------
__global__ __launch_bounds__(256) void transpose_x(const float* __restrict__ x,
                                                   float* __restrict__ feat0) {
  int t = blockIdx.x * 256 + threadIdx.x;
  if (t >= B_SZ * 3 * N_PTS) return;
  int b = t / (3 * N_PTS);
  int r = t - b * 3 * N_PTS;
  int c = r / N_PTS;
  int n = r - c * N_PTS;
  feat0[((size_t)(b * N_PTS + n)) * 4 + c] = x[t];
}

// ---------------- squared norms per point ----------------
__global__ __launch_bounds__(256) void xnorm_kernel(const float* __restrict__ feat, int lda,
                                                    int C, float* __restrict__ x2) {
  int p = blockIdx.x * 256 + threadIdx.x;
  if (p >= 8192) return;
  const float* r = feat + (size_t)p * lda;
  float s = 0.f;
  for (int c = 0; c < C; c += 4) {
    float4 v = *(const float4*)(r + c);
    s = fmaf(v.x, v.x, s); s = fmaf(v.y, v.y, s);
    s = fmaf(v.z, v.z, s); s = fmaf(v.w, v.w, s);
  }
  x2[p] = s;
}

// ---------------- pack candidates: feat (b,p,4k4..) -> pack[(b*C4+k4)*1024+p] (float4) ----
__global__ __launch_bounds__(256) void pack_kernel(const float* __restrict__ feat, int lda,
                                                   int C4, float4* __restrict__ packb) {
  int t = blockIdx.x * 256 + threadIdx.x;
  if (t >= 8192 * C4) return;
  int p = t & 1023;
  int bk = t >> 10;
  int k4 = bk % C4, b = bk / C4;
  packb[t] = *(const float4*)(feat + (size_t)(b * 1024 + p) * lda + (k4 << 2));
}

// ---- DPP argmax combine stage: comparator = max by (value desc, index asc) ----
// update_dpp old-operand = identity (-inf / INT_MAX) for invalid source lanes.
#define DPP_ARG_STAGE(CTRL)                                                          \
  {                                                                                  \
    int nvb = __builtin_amdgcn_update_dpp((int)0xFF800000, __float_as_int(bv),       \
                                          (CTRL), 0xF, 0xF, false);                  \
    int nib = __builtin_amdgcn_update_dpp((int)0x7fffffff, bi,                       \
                                          (CTRL), 0xF, 0xF, false);                  \
    float nv = __int_as_float(nvb);                                                  \
    if (nv > bv || (nv == bv && nib < bi)) { bv = nv; bi = nib; }                    \
  }

// ---------------- fused KNN: distances in-register + top-20 selection (DPP reduce) ----
// 512 threads = 8 waves; one row per wave; lane holds cols j*64+lane.
// Selection comparator/semantics bit-identical to proven rounds; reduction tree is
// row_shr:1/2/4/8 + bcast15 + bcast31 (total-order max => association-invariant),
// winner index read from lane 63.
__global__ __launch_bounds__(512) void knn_fused(const float* __restrict__ feat, int lda,
                                                 int C4, const float4* __restrict__ pack,
                                                 const float* __restrict__ x2,
                                                 int* __restrict__ idxout) {
  __shared__ float4 xms[1024];        // 16 KB: all candidates' current k-slice
  __shared__ float4 xn_sh[8 * 32];    // 4 KB: the block's 8 query rows (C4<=32)
  int tid = threadIdx.x;
  int w = tid >> 6, lane = tid & 63;
  int row0 = blockIdx.x * 8;
  int b = row0 >> 10;
  int row = row0 + w;
  const float4* packB = pack + (size_t)b * C4 * 1024;

  if (tid < 8 * C4) {
    int r = tid / C4, q = tid - r * C4;
    xn_sh[r * 32 + q] = *(const float4*)(feat + (size_t)(row0 + r) * lda + (q << 2));
  }

  float acc[16];
  #pragma unroll
  for (int j = 0; j < 16; ++j) acc[j] = 0.f;

  for (int k4 = 0; k4 < C4; ++k4) {
    xms[tid] = packB[k4 * 1024 + tid];
    xms[tid + 512] = packB[k4 * 1024 + tid + 512];
    __syncthreads();
    float4 xn = xn_sh[w * 32 + k4];
    #pragma unroll
    for (int j = 0; j < 16; ++j) {
      float4 xm = xms[j * 64 + lane];
      acc[j] = fmaf(xn.x, xm.x, acc[j]);
      acc[j] = fmaf(xn.y, xm.y, acc[j]);
      acc[j] = fmaf(xn.z, xm.z, acc[j]);
      acc[j] = fmaf(xn.w, xm.w, acc[j]);
    }
    __syncthreads();
  }

  // epilogue: pd = (2*dot - x2n) - x2m (identical expression to proven kernels)
  const float* x2b = x2 + b * N_PTS;
  float x2n = x2[row];
  #pragma unroll
  for (int j = 0; j < 16; ++j)
    acc[j] = (2.f * acc[j] - x2n) - x2b[j * 64 + lane];

  // top-20: per-lane scan (strict > keeps smallest col in-lane) + DPP tree reduce
  for (int rr = 0; rr < KNN_K; ++rr) {
    float bv = -3.4e38f;
    int bi = 0x7fffffff;
    #pragma unroll
    for (int j = 0; j < 16; ++j)
      if (acc[j] > bv) { bv = acc[j]; bi = j * 64 + lane; }

    DPP_ARG_STAGE(0x111)   // row_shr:1
    DPP_ARG_STAGE(0x112)   // row_shr:2
    DPP_ARG_STAGE(0x114)   // row_shr:4
    DPP_ARG_STAGE(0x118)   // row_shr:8
    DPP_ARG_STAGE(0x142)   // row_bcast15
    DPP_ARG_STAGE(0x143)   // row_bcast31
    int si = __builtin_amdgcn_readlane(bi, 63);   // global winner (uniform)

    int jj = si >> 6, ln = si & 63;
    bool isln = (lane == ln);
    #pragma unroll
    for (int j = 0; j < 16; ++j)
      if (j == jj && isln) acc[j] = -3.4e38f;     // uniform j==jj, compile-time index
    if (lane == 0) idxout[row * KNN_K + rr] = si;
  }
}

// ---------------- build combined weight Wc (fp32): [w1-w2 | w2], K=C rows x 2O cols ----------------
__global__ __launch_bounds__(256) void build_wc(const float* __restrict__ w, int C, int O,
                                                float* __restrict__ wc) {
  int t = blockIdx.x * 256 + threadIdx.x;
  int twoO = 2 * O;
  if (t >= C * twoO) return;
  int c = t / twoO, j = t - c * twoO;
  float v;
  if (j < O) v = w[j * (2 * C) + c] - w[j * (2 * C) + C + c];
  else       v = w[(j - O) * (2 * C) + C + c];
  wc[t] = v;
}

// ---------------- fp32 GEMM (edge layers): C[M,N] = A[M,K](lda) * B[K,N] ----------------
__global__ __launch_bounds__(256) void gemm_kernel(const float* __restrict__ A, int lda,
                                                   const float* __restrict__ Bm,
                                                   float* __restrict__ Cm,
                                                   int M, int N, int K) {
  __shared__ float As[16][64];
  __shared__ float Bs[16][68];
  int tx = threadIdx.x & 15, ty = threadIdx.x >> 4;
  int bn0 = blockIdx.x * 64, bm0 = blockIdx.y * 64;
  float acc[4][4];
  #pragma unroll
  for (int i = 0; i < 4; ++i)
    #pragma unroll
    for (int j = 0; j < 4; ++j) acc[i][j] = 0.f;

  for (int k0 = 0; k0 < K; k0 += 16) {
    {
      int t = threadIdx.x;
      int m = t >> 2, kb = (t & 3) * 4;
      const float* ap = A + (size_t)(bm0 + m) * lda + k0 + kb;
      #pragma unroll
      for (int i = 0; i < 4; ++i) As[kb + i][m] = (k0 + kb + i < K) ? ap[i] : 0.f;
      int r = t >> 4, c4 = (t & 15) * 4;
      float4 bv = make_float4(0.f, 0.f, 0.f, 0.f);
      if (k0 + r < K) bv = *(const float4*)(Bm + (size_t)(k0 + r) * N + bn0 + c4);
      *(float4*)&Bs[r][c4] = bv;
    }
    __syncthreads();
    #pragma unroll
    for (int k = 0; k < 16; ++k) {
      float a0[4];
      #pragma unroll
      for (int i = 0; i < 4; ++i) a0[i] = As[k][ty * 4 + i];
      float4 bv = *(const float4*)&Bs[k][tx * 4];
      float b0[4] = {bv.x, bv.y, bv.z, bv.w};
      #pragma unroll
      for (int i = 0; i < 4; ++i)
        #pragma unroll
        for (int j = 0; j < 4; ++j) acc[i][j] = fmaf(a0[i], b0[j], acc[i][j]);
    }
    __syncthreads();
  }
  #pragma unroll
  for (int i = 0; i < 4; ++i) {
    float4 v = make_float4(acc[i][0], acc[i][1], acc[i][2], acc[i][3]);
    *(float4*)(Cm + (size_t)(bm0 + ty * 4 + i) * N + bn0 + tx * 4) = v;
  }
}

// ---------------- split fp32 -> bf16 hi/lo MFMA GEMM for layer 5, fused reduction ----------------
__device__ inline void split8(const float* __restrict__ p, bf16x8* hv, bf16x8* lv) {
  float4 a0 = *(const float4*)p, a1 = *(const float4*)(p + 4);
  float v[8] = {a0.x, a0.y, a0.z, a0.w, a1.x, a1.y, a1.z, a1.w};
  bf16x8 h, l;
  #pragma unroll
  for (int j = 0; j < 8; ++j) {
    __bf16 hj = (__bf16)v[j];
    h[j] = hj;
    l[j] = (__bf16)(v[j] - (float)hj);
  }
  *hv = h; *lv = l;
}

__global__ __launch_bounds__(256) void gemm_split_red(const float* __restrict__ A, int lda,
                                                      const float* __restrict__ Bt, int ldb,
                                                      float* __restrict__ parts, int K) {
  __shared__ u16 Ah[128 * 64];
  __shared__ u16 Al[128 * 64];
  __shared__ u16 Bh[128 * 64];
  __shared__ u16 Bl[128 * 64];
  int tid = threadIdx.x;
  int wave = tid >> 6, lane = tid & 63;
  int wr = wave >> 1, wc = wave & 1;
  int bn0 = blockIdx.x * 128, bm0 = blockIdx.y * 128;
  int lrow = lane & 15;
  int kgrp = lane >> 4;

  f32x4 acc[4][4];
  #pragma unroll
  for (int i = 0; i < 4; ++i)
    #pragma unroll
    for (int j = 0; j < 4; ++j) acc[i][j] = (f32x4){0.f, 0.f, 0.f, 0.f};

  for (int k0 = 0; k0 < K; k0 += 64) {
    #pragma unroll
    for (int i = 0; i < 4; ++i) {
      int chunk = tid + i * 256;        // 0..1023
      int row = chunk >> 3;             // 0..127
      int cc = (chunk & 7) * 8;         // fp32 col 0,8,..,56
      int byte = row * 128 + ((cc * 2) ^ ((row & 7) << 4));
      bf16x8 h, l;
      split8(A + (size_t)(bm0 + row) * lda + k0 + cc, &h, &l);
      *(bf16x8*)((char*)Ah + byte) = h;
      *(bf16x8*)((char*)Al + byte) = l;
      split8(Bt + (size_t)(bn0 + row) * ldb + k0 + cc, &h, &l);
      *(bf16x8*)((char*)Bh + byte) = h;
      *(bf16x8*)((char*)Bl + byte) = l;
    }
    __syncthreads();
    #pragma unroll
    for (int kk = 0; kk < 64; kk += 32) {
      int kb = (kk + kgrp * 8) * 2;
      bf16x8 afh[4], afl[4], bfh[4], bfl[4];
      #pragma unroll
      for (int f = 0; f < 4; ++f) {
        int arow = wr * 64 + f * 16 + lrow;
        int abyte = arow * 128 + (kb ^ ((arow & 7) << 4));
        afh[f] = *(const bf16x8*)((const char*)Ah + abyte);
        afl[f] = *(const bf16x8*)((const char*)Al + abyte);
        int brow = wc * 64 + f * 16 + lrow;
        int bbyte = brow * 128 + (kb ^ ((brow & 7) << 4));
        bfh[f] = *(const bf16x8*)((const char*)Bh + bbyte);
        bfl[f] = *(const bf16x8*)((const char*)Bl + bbyte);
      }
      #pragma unroll
      for (int fm = 0; fm < 4; ++fm)
        #pragma unroll
        for (int fn = 0; fn < 4; ++fn) {
          acc[fm][fn] = __builtin_amdgcn_mfma_f32_16x16x32_bf16(afh[fm], bfh[fn], acc[fm][fn], 0, 0, 0);
          acc[fm][fn] = __builtin_amdgcn_mfma_f32_16x16x32_bf16(afl[fm], bfh[fn], acc[fm][fn], 0, 0, 0);
          acc[fm][fn] = __builtin_amdgcn_mfma_f32_16x16x32_bf16(afh[fm], bfl[fn], acc[fm][fn], 0, 0, 0);
        }
    }
    __syncthreads();
  }

  // fused per-tile reduction over the 128 rows
  float* scratch = (float*)Ah;
  int contrib = wr * 4 + kgrp;
  #pragma unroll
  for (int fn = 0; fn < 4; ++fn) {
    float mx = -3.4e38f, mn = 3.4e38f, s1 = 0.f, s2 = 0.f;
    #pragma unroll
    for (int fm = 0; fm < 4; ++fm)
      #pragma unroll
      for (int r = 0; r < 4; ++r) {
        float v = acc[fm][fn][r];
        mx = fmaxf(mx, v); mn = fminf(mn, v);
        s1 += v; s2 = fmaf(v, v, s2);
      }
    int col = wc * 64 + fn * 16 + lrow;
    float* sp = scratch + (contrib * 128 + col) * 4;
    sp[0] = mx; sp[1] = mn; sp[2] = s1; sp[3] = s2;
  }
  __syncthreads();
  if (tid < 128) {
    float mx = -3.4e38f, mn = 3.4e38f, s1 = 0.f, s2 = 0.f;
    #pragma unroll
    for (int c2 = 0; c2 < 8; ++c2) {
      const float* sp = scratch + (c2 * 128 + tid) * 4;
      mx = fmaxf(mx, sp[0]); mn = fminf(mn, sp[1]);
      s1 += sp[2]; s2 += sp[3];
    }
    size_t o = (size_t)blockIdx.y * 1024 + bn0 + tid;
    parts[o] = mx;
    parts[65536 + o] = mn;
    parts[131072 + o] = s1;
    parts[196608 + o] = s2;
  }
}

// ---------------- edge aggregation: h = a + y[idx]; max/min over k + channel sums ----------------
__global__ __launch_bounds__(256) void aggregate_kernel(const float* __restrict__ ay,
                                                        const int* __restrict__ idxb, int O,
                                                        float* __restrict__ mx,
                                                        float* __restrict__ mn,
                                                        float* __restrict__ sumsbin) {
  __shared__ float ls[2][256];
  for (int i = threadIdx.x; i < 512; i += 256) ((float*)ls)[i] = 0.f;
  __syncthreads();

  int warp = threadIdx.x >> 6, lane = threadIdx.x & 63;
  int pt = blockIdx.x * 4 + warp;   // 0..8191
  int b = pt >> 10;
  int twoO = 2 * O;
  int U = O >> 6;
  const float* ayrow = ay + (size_t)pt * twoO;

  float av[4], s1[4], s2[4], vmx[4], vmn[4];
  for (int u = 0; u < U; ++u) {
    av[u] = ayrow[u * 64 + lane];
    s1[u] = 0.f; s2[u] = 0.f; vmx[u] = -3.4e38f; vmn[u] = 3.4e38f;
  }
  const int* ip = idxb + pt * KNN_K;
  for (int k = 0; k < KNN_K; ++k) {
    int j = ip[k];
    const float* yrow = ay + (size_t)(b * N_PTS + j) * twoO + O;
    for (int u = 0; u < U; ++u) {
      float v = av[u] + yrow[u * 64 + lane];
      s1[u] += v; s2[u] = fmaf(v, v, s2[u]);
      vmx[u] = fmaxf(vmx[u], v); vmn[u] = fminf(vmn[u], v);
    }
  }
  for (int u = 0; u < U; ++u) {
    int o = u * 64 + lane;
    mx[(size_t)pt * O + o] = vmx[u];
    mn[(size_t)pt * O + o] = vmn[u];
    atomicAdd(&ls[0][o], s1[u]);
    atomicAdd(&ls[1][o], s2[u]);
  }
  __syncthreads();
  int bin = blockIdx.x & 63;
  float* gb = sumsbin + (size_t)bin * 512;
  for (int o = threadIdx.x; o < O; o += 256) {
    atomicAdd(&gb[o], ls[0][o]);
    atomicAdd(&gb[256 + o], ls[1][o]);
  }
}

__global__ __launch_bounds__(256) void reduce_bins(const float* __restrict__ sumsbin,
                                                   float* __restrict__ sums, int O) {
  int o = threadIdx.x;
  if (o >= O) return;
  float a = 0.f, c = 0.f;
  for (int bin = 0; bin < 64; ++bin) {
    a += sumsbin[bin * 512 + o];
    c += sumsbin[bin * 512 + 256 + o];
  }
  sums[o] = a;
  sums[256 + o] = c;
}

// ---------------- finalize edge layer: BN + relu on (max or min depending on sign) ----------------
__global__ __launch_bounds__(256) void finalize_edge(const float* __restrict__ mx,
                                                     const float* __restrict__ mn,
                                                     const float* __restrict__ sums,
                                                     const float* __restrict__ g,
                                                     const float* __restrict__ beta,
                                                     int oshift,
                                                     float* __restrict__ outseg,
                                                     float cnt_inv) {
  int tid = blockIdx.x * 256 + threadIdx.x;
  int pt = tid >> oshift;
  int o = tid & ((1 << oshift) - 1);
  float s1 = sums[o], s2 = sums[256 + o];
  float mean = s1 * cnt_inv;
  float var = s2 * cnt_inv - mean * mean;
  float rstd = rsqrtf(var + BN_EPS);
  float sc = g[o] * rstd;
  float sel = (sc >= 0.f) ? mx[tid] : mn[tid];
  float v = (sel - mean) * sc + beta[o];
  outseg[(size_t)pt * CAT_C + o] = fmaxf(v, 0.f);
}

// ---------------- layer 5 finalize from tile partials ----------------
__global__ __launch_bounds__(256) void finalize5_fused(const float* __restrict__ parts,
                                                       const float* __restrict__ g,
                                                       const float* __restrict__ beta,
                                                       float* __restrict__ out) {
  int tid = blockIdx.x * 256 + threadIdx.x;   // 0..8191
  int b = tid >> 10, o = tid & 1023;
  const float* pmx = parts;
  const float* pmn = parts + 65536;
  const float* ps1 = parts + 131072;
  const float* ps2 = parts + 196608;
  float s1 = 0.f, s2 = 0.f;
  for (int t = 0; t < 64; ++t) { s1 += ps1[t * 1024 + o]; s2 += ps2[t * 1024 + o]; }
  float mx = -3.4e38f, mn = 3.4e38f;
  #pragma unroll
  for (int t = 0; t < 8; ++t) {
    mx = fmaxf(mx, pmx[(b * 8 + t) * 1024 + o]);
    mn = fminf(mn, pmn[(b * 8 + t) * 1024 + o]);
  }
  float mean = s1 * (1.0f / 8192.0f);
  float var = s2 * (1.0f / 8192.0f) - mean * mean;
  float rstd = rsqrtf(var + BN_EPS);
  float sc = g[o] * rstd;
  float sel = (sc >= 0.f) ? mx : mn;
  float v = (sel - mean) * sc + beta[o];
  out[tid] = fmaxf(v, 0.f);
}

extern "C" void kernel_launch(void* const* d_in, const int* in_sizes, int n_in,
                              void* d_out, int out_size, void* d_ws, size_t ws_size,
                              hipStream_t stream) {
  const float* x = (const float*)d_in[0];
  const float* w[5]  = {(const float*)d_in[1], (const float*)d_in[4], (const float*)d_in[7],
                        (const float*)d_in[10], (const float*)d_in[13]};
  const float* gg[5] = {(const float*)d_in[2], (const float*)d_in[5], (const float*)d_in[8],
                        (const float*)d_in[11], (const float*)d_in[14]};
  const float* bb[5] = {(const float*)d_in[3], (const float*)d_in[6], (const float*)d_in[9],
                        (const float*)d_in[12], (const float*)d_in[15]};
  float* out = (float*)d_out;

  float* W = (float*)d_ws;
  size_t off = 0;
  float* feat0   = W + off; off += (size_t)B_SZ * N_PTS * 4;   // stride-4 padded
  float* catbuf  = W + off; off += (size_t)8192 * CAT_C;
  int*   idxbuf  = (int*)(W + off); off += (size_t)8192 * KNN_K;
  float* aybuf   = W + off; off += (size_t)8192 * 1024;
  float* mxbuf   = W + off; off += (size_t)8192 * 256;
  float* mnbuf   = W + off; off += (size_t)8192 * 256;
  float* wcbuf   = W + off; off += (size_t)512 * 1024;
  float* sumsbin = W + off; off += (size_t)64 * 512;
  float* sums    = W + off; off += 512;
  float* parts   = W + off; off += (size_t)4 * 64 * 1024;  // L5 tile partials (mx,mn,s1,s2)
  float* x2buf   = W + off; off += 8192;
  float4* packbuf = (float4*)(W + off); off += (size_t)8192 * 32 * 4;  // [b][k4][1024] f4, 4MB

  hipMemsetAsync(feat0, 0, (size_t)B_SZ * N_PTS * 4 * sizeof(float), stream);
  transpose_x<<<(B_SZ * 3 * N_PTS + 255) / 256, 256, 0, stream>>>(x, feat0);

  const int Cs[4] = {4, 64, 64, 128};   // layer-0 padded to 4 (pad=0, values unchanged)
  const int Ks[4] = {3, 64, 64, 128};   // true K for the edge GEMM
  const int Os[4] = {64, 64, 128, 256};
  const int osh[4] = {6, 6, 7, 8};
  const int segin[4] = {0, 0, 64, 128};
  const int segout[4] = {0, 64, 128, 256};

  for (int l = 0; l < 4; ++l) {
    int C = Cs[l], O = Os[l], twoO = 2 * O;
    const float* featin = (l == 0) ? feat0 : (catbuf + segin[l]);
    int lda = (l == 0) ? 4 : CAT_C;
    int C4 = C / 4;

    xnorm_kernel<<<32, 256, 0, stream>>>(featin, lda, C, x2buf);
    pack_kernel<<<(8192 * C4 + 255) / 256, 256, 0, stream>>>(featin, lda, C4, packbuf);
    knn_fused<<<1024, 512, 0, stream>>>(featin, lda, C4, packbuf, x2buf, idxbuf);

    build_wc<<<(Ks[l] * twoO + 255) / 256, 256, 0, stream>>>(w[l], Ks[l], O, wcbuf);
    gemm_kernel<<<dim3(twoO / 64, 8192 / 64), 256, 0, stream>>>(featin, lda, wcbuf, aybuf,
                                                                8192, twoO, Ks[l]);
    hipMemsetAsync(sumsbin, 0, (size_t)64 * 512 * sizeof(float), stream);
    aggregate_kernel<<<2048, 256, 0, stream>>>(aybuf, idxbuf, O, mxbuf, mnbuf, sumsbin);
    reduce_bins<<<1, 256, 0, stream>>>(sumsbin, sums, O);
    finalize_edge<<<(8192 * O) / 256, 256, 0, stream>>>(mxbuf, mnbuf, sums, gg[l], bb[l],
                                                        osh[l], catbuf + segout[l],
                                                        1.0f / (8192.0f * KNN_K));
  }

  // layer 5: h5 = cat * w5^T via split-bf16 MFMA with fused per-tile reduction
  gemm_split_red<<<dim3(1024 / 128, 8192 / 128), 256, 0, stream>>>(catbuf, CAT_C, w[4], 512,
                                                                   parts, 512);
  finalize5_fused<<<8192 / 256, 256, 0, stream>>>(parts, gg[4], bb[4], out);
}

// Round 11
// 552.396 us; speedup vs baseline: 1.3442x; 1.0697x over previous
//
#include <hip/hip_runtime.h>
#include <cstddef>

#define B_SZ 8
#define N_PTS 1024
#define KNN_K 20
#define CAT_C 512
#define BN_EPS 1e-5f

typedef unsigned short u16;
typedef unsigned int u32;
typedef __bf16 bf16x8 __attribute__((ext_vector_type(8)));
typedef float f32x4 __attribute__((ext_vector_type(4)));

// ---------------- transpose x (B,3,N) -> feat0 (B,N,4) (col 3 pre-zeroed) ----------------
__global__ __launch_bounds__(256) void transpose_x(const float* __restrict__ x,
                                                   float* __restrict__ feat0) {
  int t = blockIdx.x * 256 + threadIdx.x;
  if (t >= B_SZ * 3 * N_PTS) return;
  int b = t / (3 * N_PTS);
  int r = t - b * 3 * N_PTS;
  int c = r / N_PTS;
  int n = r - c * N_PTS;
  feat0[((size_t)(b * N_PTS + n)) * 4 + c] = x[t];
}

// ---------------- squared norms per point ----------------
__global__ __launch_bounds__(256) void xnorm_kernel(const float* __restrict__ feat, int lda,
                                                    int C, float* __restrict__ x2) {
  int p = blockIdx.x * 256 + threadIdx.x;
  if (p >= 8192) return;
  const float* r = feat + (size_t)p * lda;
  float s = 0.f;
  for (int c = 0; c < C; c += 4) {
    float4 v = *(const float4*)(r + c);
    s = fmaf(v.x, v.x, s); s = fmaf(v.y, v.y, s);
    s = fmaf(v.z, v.z, s); s = fmaf(v.w, v.w, s);
  }
  x2[p] = s;
}

// ---------------- pack candidates: feat (b,p,4k4..) -> pack[(b*C4+k4)*1024+p] (float4) ----
__global__ __launch_bounds__(256) void pack_kernel(const float* __restrict__ feat, int lda,
                                                   int C4, float4* __restrict__ packb) {
  int t = blockIdx.x * 256 + threadIdx.x;
  if (t >= 8192 * C4) return;
  int p = t & 1023;
  int bk = t >> 10;
  int k4 = bk % C4, b = bk / C4;
  packb[t] = *(const float4*)(feat + (size_t)(b * 1024 + p) * lda + (k4 << 2));
}

// ---- value-only DPP reduce stages (single v_max/v_min per stage + identity mov) ----
// Tree (row_shr:1/2/4/8 + bcast15 + bcast31 -> lane 63) is the sequence HW-verified
// in R10 (absmax matched the shfl version bit-exactly).
#define DPP_MAX_STAGE(CTRL)                                                          \
  {                                                                                  \
    int nb = __builtin_amdgcn_update_dpp((int)0xFF800000, __float_as_int(mx),        \
                                         (CTRL), 0xF, 0xF, false);                   \
    mx = fmaxf(mx, __int_as_float(nb));                                              \
  }
#define DPP_MIN_STAGE(CTRL)                                                          \
  {                                                                                  \
    int nb = __builtin_amdgcn_update_dpp((int)0x7fffffff, mi,                        \
                                         (CTRL), 0xF, 0xF, false);                   \
    mi = (nb < mi) ? nb : mi;                                                        \
  }

// ---------------- fused KNN: distances in-register + top-20 selection ----------------
// 512 threads = 8 waves; one row per wave; lane holds cols j*64+lane.
// Selection = value-max reduce, then min-global-col among value-equal (== previous
// tie-break: smallest index among ties; ordering by (j<<6)|lane == global col order).
__global__ __launch_bounds__(512) void knn_fused(const float* __restrict__ feat, int lda,
                                                 int C4, const float4* __restrict__ pack,
                                                 const float* __restrict__ x2,
                                                 int* __restrict__ idxout) {
  __shared__ float4 xms[1024];        // 16 KB: all candidates' current k-slice
  __shared__ float4 xn_sh[8 * 32];    // 4 KB: the block's 8 query rows (C4<=32)
  int tid = threadIdx.x;
  int w = tid >> 6, lane = tid & 63;
  int row0 = blockIdx.x * 8;
  int b = row0 >> 10;
  int row = row0 + w;
  const float4* packB = pack + (size_t)b * C4 * 1024;

  if (tid < 8 * C4) {
    int r = tid / C4, q = tid - r * C4;
    xn_sh[r * 32 + q] = *(const float4*)(feat + (size_t)(row0 + r) * lda + (q << 2));
  }

  float acc[16];
  #pragma unroll
  for (int j = 0; j < 16; ++j) acc[j] = 0.f;

  for (int k4 = 0; k4 < C4; ++k4) {
    xms[tid] = packB[k4 * 1024 + tid];
    xms[tid + 512] = packB[k4 * 1024 + tid + 512];
    __syncthreads();
    float4 xn = xn_sh[w * 32 + k4];
    #pragma unroll
    for (int j = 0; j < 16; ++j) {
      float4 xm = xms[j * 64 + lane];
      acc[j] = fmaf(xn.x, xm.x, acc[j]);
      acc[j] = fmaf(xn.y, xm.y, acc[j]);
      acc[j] = fmaf(xn.z, xm.z, acc[j]);
      acc[j] = fmaf(xn.w, xm.w, acc[j]);
    }
    __syncthreads();
  }

  // epilogue: pd = (2*dot - x2n) - x2m (identical expression to proven kernels)
  const float* x2b = x2 + b * N_PTS;
  float x2n = x2[row];
  #pragma unroll
  for (int j = 0; j < 16; ++j)
    acc[j] = (2.f * acc[j] - x2n) - x2b[j * 64 + lane];

  // top-20: value-only max reduce + min-col-among-equal (bit-identical winner set)
  for (int rr = 0; rr < KNN_K; ++rr) {
    // per-lane max (pure fmax tree; v_max3-fusable)
    float m01 = fmaxf(acc[0], acc[1]),   m23 = fmaxf(acc[2], acc[3]);
    float m45 = fmaxf(acc[4], acc[5]),   m67 = fmaxf(acc[6], acc[7]);
    float m89 = fmaxf(acc[8], acc[9]),   mab = fmaxf(acc[10], acc[11]);
    float mcd = fmaxf(acc[12], acc[13]), mef = fmaxf(acc[14], acc[15]);
    float mx = fmaxf(fmaxf(fmaxf(m01, m23), fmaxf(m45, m67)),
                     fmaxf(fmaxf(m89, mab), fmaxf(mcd, mef)));
    DPP_MAX_STAGE(0x111)   // row_shr:1
    DPP_MAX_STAGE(0x112)   // row_shr:2
    DPP_MAX_STAGE(0x114)   // row_shr:4
    DPP_MAX_STAGE(0x118)   // row_shr:8
    DPP_MAX_STAGE(0x142)   // row_bcast15
    DPP_MAX_STAGE(0x143)   // row_bcast31
    mx = __int_as_float(__builtin_amdgcn_readlane(__float_as_int(mx), 63)); // uniform

    // per-lane smallest j with acc[j]==mx (descending scan keeps smallest)
    int jloc = 16;
    #pragma unroll
    for (int j = 15; j >= 0; --j)
      if (acc[j] == mx) jloc = j;
    int mi = (jloc < 16) ? ((jloc << 6) | lane) : 0x7fffffff;  // global col or +inf
    DPP_MIN_STAGE(0x111)
    DPP_MIN_STAGE(0x112)
    DPP_MIN_STAGE(0x114)
    DPP_MIN_STAGE(0x118)
    DPP_MIN_STAGE(0x142)
    DPP_MIN_STAGE(0x143)
    int si = __builtin_amdgcn_readlane(mi, 63);   // winner global col (uniform)

    int jj = si >> 6, ln = si & 63;
    bool isln = (lane == ln);
    #pragma unroll
    for (int j = 0; j < 16; ++j)
      if (j == jj && isln) acc[j] = -3.4e38f;     // uniform j==jj, compile-time index
    if (lane == 0) idxout[row * KNN_K + rr] = si;
  }
}

// ---------------- build combined weight Wc (fp32): [w1-w2 | w2], K=C rows x 2O cols ----------------
__global__ __launch_bounds__(256) void build_wc(const float* __restrict__ w, int C, int O,
                                                float* __restrict__ wc) {
  int t = blockIdx.x * 256 + threadIdx.x;
  int twoO = 2 * O;
  if (t >= C * twoO) return;
  int c = t / twoO, j = t - c * twoO;
  float v;
  if (j < O) v = w[j * (2 * C) + c] - w[j * (2 * C) + C + c];
  else       v = w[(j - O) * (2 * C) + C + c];
  wc[t] = v;
}

// ---------------- fp32 GEMM (edge layers): C[M,N] = A[M,K](lda) * B[K,N] ----------------
__global__ __launch_bounds__(256) void gemm_kernel(const float* __restrict__ A, int lda,
                                                   const float* __restrict__ Bm,
                                                   float* __restrict__ Cm,
                                                   int M, int N, int K) {
  __shared__ float As[16][64];
  __shared__ float Bs[16][68];
  int tx = threadIdx.x & 15, ty = threadIdx.x >> 4;
  int bn0 = blockIdx.x * 64, bm0 = blockIdx.y * 64;
  float acc[4][4];
  #pragma unroll
  for (int i = 0; i < 4; ++i)
    #pragma unroll
    for (int j = 0; j < 4; ++j) acc[i][j] = 0.f;

  for (int k0 = 0; k0 < K; k0 += 16) {
    {
      int t = threadIdx.x;
      int m = t >> 2, kb = (t & 3) * 4;
      const float* ap = A + (size_t)(bm0 + m) * lda + k0 + kb;
      #pragma unroll
      for (int i = 0; i < 4; ++i) As[kb + i][m] = (k0 + kb + i < K) ? ap[i] : 0.f;
      int r = t >> 4, c4 = (t & 15) * 4;
      float4 bv = make_float4(0.f, 0.f, 0.f, 0.f);
      if (k0 + r < K) bv = *(const float4*)(Bm + (size_t)(k0 + r) * N + bn0 + c4);
      *(float4*)&Bs[r][c4] = bv;
    }
    __syncthreads();
    #pragma unroll
    for (int k = 0; k < 16; ++k) {
      float a0[4];
      #pragma unroll
      for (int i = 0; i < 4; ++i) a0[i] = As[k][ty * 4 + i];
      float4 bv = *(const float4*)&Bs[k][tx * 4];
      float b0[4] = {bv.x, bv.y, bv.z, bv.w};
      #pragma unroll
      for (int i = 0; i < 4; ++i)
        #pragma unroll
        for (int j = 0; j < 4; ++j) acc[i][j] = fmaf(a0[i], b0[j], acc[i][j]);
    }
    __syncthreads();
  }
  #pragma unroll
  for (int i = 0; i < 4; ++i) {
    float4 v = make_float4(acc[i][0], acc[i][1], acc[i][2], acc[i][3]);
    *(float4*)(Cm + (size_t)(bm0 + ty * 4 + i) * N + bn0 + tx * 4) = v;
  }
}

// ---------------- split fp32 -> bf16 hi/lo MFMA GEMM for layer 5, fused reduction ----------------
__device__ inline void split8(const float* __restrict__ p, bf16x8* hv, bf16x8* lv) {
  float4 a0 = *(const float4*)p, a1 = *(const float4*)(p + 4);
  float v[8] = {a0.x, a0.y, a0.z, a0.w, a1.x, a1.y, a1.z, a1.w};
  bf16x8 h, l;
  #pragma unroll
  for (int j = 0; j < 8; ++j) {
    __bf16 hj = (__bf16)v[j];
    h[j] = hj;
    l[j] = (__bf16)(v[j] - (float)hj);
  }
  *hv = h; *lv = l;
}

__global__ __launch_bounds__(256) void gemm_split_red(const float* __restrict__ A, int lda,
                                                      const float* __restrict__ Bt, int ldb,
                                                      float* __restrict__ parts, int K) {
  __shared__ u16 Ah[128 * 64];
  __shared__ u16 Al[128 * 64];
  __shared__ u16 Bh[128 * 64];
  __shared__ u16 Bl[128 * 64];
  int tid = threadIdx.x;
  int wave = tid >> 6, lane = tid & 63;
  int wr = wave >> 1, wc = wave & 1;
  int bn0 = blockIdx.x * 128, bm0 = blockIdx.y * 128;
  int lrow = lane & 15;
  int kgrp = lane >> 4;

  f32x4 acc[4][4];
  #pragma unroll
  for (int i = 0; i < 4; ++i)
    #pragma unroll
    for (int j = 0; j < 4; ++j) acc[i][j] = (f32x4){0.f, 0.f, 0.f, 0.f};

  for (int k0 = 0; k0 < K; k0 += 64) {
    #pragma unroll
    for (int i = 0; i < 4; ++i) {
      int chunk = tid + i * 256;        // 0..1023
      int row = chunk >> 3;             // 0..127
      int cc = (chunk & 7) * 8;         // fp32 col 0,8,..,56
      int byte = row * 128 + ((cc * 2) ^ ((row & 7) << 4));
      bf16x8 h, l;
      split8(A + (size_t)(bm0 + row) * lda + k0 + cc, &h, &l);
      *(bf16x8*)((char*)Ah + byte) = h;
      *(bf16x8*)((char*)Al + byte) = l;
      split8(Bt + (size_t)(bn0 + row) * ldb + k0 + cc, &h, &l);
      *(bf16x8*)((char*)Bh + byte) = h;
      *(bf16x8*)((char*)Bl + byte) = l;
    }
    __syncthreads();
    #pragma unroll
    for (int kk = 0; kk < 64; kk += 32) {
      int kb = (kk + kgrp * 8) * 2;
      bf16x8 afh[4], afl[4], bfh[4], bfl[4];
      #pragma unroll
      for (int f = 0; f < 4; ++f) {
        int arow = wr * 64 + f * 16 + lrow;
        int abyte = arow * 128 + (kb ^ ((arow & 7) << 4));
        afh[f] = *(const bf16x8*)((const char*)Ah + abyte);
        afl[f] = *(const bf16x8*)((const char*)Al + abyte);
        int brow = wc * 64 + f * 16 + lrow;
        int bbyte = brow * 128 + (kb ^ ((brow & 7) << 4));
        bfh[f] = *(const bf16x8*)((const char*)Bh + bbyte);
        bfl[f] = *(const bf16x8*)((const char*)Bl + bbyte);
      }
      #pragma unroll
      for (int fm = 0; fm < 4; ++fm)
        #pragma unroll
        for (int fn = 0; fn < 4; ++fn) {
          acc[fm][fn] = __builtin_amdgcn_mfma_f32_16x16x32_bf16(afh[fm], bfh[fn], acc[fm][fn], 0, 0, 0);
          acc[fm][fn] = __builtin_amdgcn_mfma_f32_16x16x32_bf16(afl[fm], bfh[fn], acc[fm][fn], 0, 0, 0);
          acc[fm][fn] = __builtin_amdgcn_mfma_f32_16x16x32_bf16(afh[fm], bfl[fn], acc[fm][fn], 0, 0, 0);
        }
    }
    __syncthreads();
  }

  // fused per-tile reduction over the 128 rows
  float* scratch = (float*)Ah;
  int contrib = wr * 4 + kgrp;
  #pragma unroll
  for (int fn = 0; fn < 4; ++fn) {
    float mx = -3.4e38f, mn = 3.4e38f, s1 = 0.f, s2 = 0.f;
    #pragma unroll
    for (int fm = 0; fm < 4; ++fm)
      #pragma unroll
      for (int r = 0; r < 4; ++r) {
        float v = acc[fm][fn][r];
        mx = fmaxf(mx, v); mn = fminf(mn, v);
        s1 += v; s2 = fmaf(v, v, s2);
      }
    int col = wc * 64 + fn * 16 + lrow;
    float* sp = scratch + (contrib * 128 + col) * 4;
    sp[0] = mx; sp[1] = mn; sp[2] = s1; sp[3] = s2;
  }
  __syncthreads();
  if (tid < 128) {
    float mx = -3.4e38f, mn = 3.4e38f, s1 = 0.f, s2 = 0.f;
    #pragma unroll
    for (int c2 = 0; c2 < 8; ++c2) {
      const float* sp = scratch + (c2 * 128 + tid) * 4;
      mx = fmaxf(mx, sp[0]); mn = fminf(mn, sp[1]);
      s1 += sp[2]; s2 += sp[3];
    }
    size_t o = (size_t)blockIdx.y * 1024 + bn0 + tid;
    parts[o] = mx;
    parts[65536 + o] = mn;
    parts[131072 + o] = s1;
    parts[196608 + o] = s2;
  }
}

// ---------------- edge aggregation: h = a + y[idx]; max/min over k + channel sums ----------------
__global__ __launch_bounds__(256) void aggregate_kernel(const float* __restrict__ ay,
                                                        const int* __restrict__ idxb, int O,
                                                        float* __restrict__ mx,
                                                        float* __restrict__ mn,
                                                        float* __restrict__ sumsbin) {
  __shared__ float ls[2][256];
  for (int i = threadIdx.x; i < 512; i += 256) ((float*)ls)[i] = 0.f;
  __syncthreads();

  int warp = threadIdx.x >> 6, lane = threadIdx.x & 63;
  int pt = blockIdx.x * 4 + warp;   // 0..8191
  int b = pt >> 10;
  int twoO = 2 * O;
  int U = O >> 6;
  const float* ayrow = ay + (size_t)pt * twoO;

  float av[4], s1[4], s2[4], vmx[4], vmn[4];
  for (int u = 0; u < U; ++u) {
    av[u] = ayrow[u * 64 + lane];
    s1[u] = 0.f; s2[u] = 0.f; vmx[u] = -3.4e38f; vmn[u] = 3.4e38f;
  }
  const int* ip = idxb + pt * KNN_K;
  for (int k = 0; k < KNN_K; ++k) {
    int j = ip[k];
    const float* yrow = ay + (size_t)(b * N_PTS + j) * twoO + O;
    for (int u = 0; u < U; ++u) {
      float v = av[u] + yrow[u * 64 + lane];
      s1[u] += v; s2[u] = fmaf(v, v, s2[u]);
      vmx[u] = fmaxf(vmx[u], v); vmn[u] = fminf(vmn[u], v);
    }
  }
  for (int u = 0; u < U; ++u) {
    int o = u * 64 + lane;
    mx[(size_t)pt * O + o] = vmx[u];
    mn[(size_t)pt * O + o] = vmn[u];
    atomicAdd(&ls[0][o], s1[u]);
    atomicAdd(&ls[1][o], s2[u]);
  }
  __syncthreads();
  int bin = blockIdx.x & 63;
  float* gb = sumsbin + (size_t)bin * 512;
  for (int o = threadIdx.x; o < O; o += 256) {
    atomicAdd(&gb[o], ls[0][o]);
    atomicAdd(&gb[256 + o], ls[1][o]);
  }
}

__global__ __launch_bounds__(256) void reduce_bins(const float* __restrict__ sumsbin,
                                                   float* __restrict__ sums, int O) {
  int o = threadIdx.x;
  if (o >= O) return;
  float a = 0.f, c = 0.f;
  for (int bin = 0; bin < 64; ++bin) {
    a += sumsbin[bin * 512 + o];
    c += sumsbin[bin * 512 + 256 + o];
  }
  sums[o] = a;
  sums[256 + o] = c;
}

// ---------------- finalize edge layer: BN + relu on (max or min depending on sign) ----------------
__global__ __launch_bounds__(256) void finalize_edge(const float* __restrict__ mx,
                                                     const float* __restrict__ mn,
                                                     const float* __restrict__ sums,
                                                     const float* __restrict__ g,
                                                     const float* __restrict__ beta,
                                                     int oshift,
                                                     float* __restrict__ outseg,
                                                     float cnt_inv) {
  int tid = blockIdx.x * 256 + threadIdx.x;
  int pt = tid >> oshift;
  int o = tid & ((1 << oshift) - 1);
  float s1 = sums[o], s2 = sums[256 + o];
  float mean = s1 * cnt_inv;
  float var = s2 * cnt_inv - mean * mean;
  float rstd = rsqrtf(var + BN_EPS);
  float sc = g[o] * rstd;
  float sel = (sc >= 0.f) ? mx[tid] : mn[tid];
  float v = (sel - mean) * sc + beta[o];
  outseg[(size_t)pt * CAT_C + o] = fmaxf(v, 0.f);
}

// ---------------- layer 5 finalize from tile partials ----------------
__global__ __launch_bounds__(256) void finalize5_fused(const float* __restrict__ parts,
                                                       const float* __restrict__ g,
                                                       const float* __restrict__ beta,
                                                       float* __restrict__ out) {
  int tid = blockIdx.x * 256 + threadIdx.x;   // 0..8191
  int b = tid >> 10, o = tid & 1023;
  const float* pmx = parts;
  const float* pmn = parts + 65536;
  const float* ps1 = parts + 131072;
  const float* ps2 = parts + 196608;
  float s1 = 0.f, s2 = 0.f;
  for (int t = 0; t < 64; ++t) { s1 += ps1[t * 1024 + o]; s2 += ps2[t * 1024 + o]; }
  float mx = -3.4e38f, mn = 3.4e38f;
  #pragma unroll
  for (int t = 0; t < 8; ++t) {
    mx = fmaxf(mx, pmx[(b * 8 + t) * 1024 + o]);
    mn = fminf(mn, pmn[(b * 8 + t) * 1024 + o]);
  }
  float mean = s1 * (1.0f / 8192.0f);
  float var = s2 * (1.0f / 8192.0f) - mean * mean;
  float rstd = rsqrtf(var + BN_EPS);
  float sc = g[o] * rstd;
  float sel = (sc >= 0.f) ? mx : mn;
  float v = (sel - mean) * sc + beta[o];
  out[tid] = fmaxf(v, 0.f);
}

extern "C" void kernel_launch(void* const* d_in, const int* in_sizes, int n_in,
                              void* d_out, int out_size, void* d_ws, size_t ws_size,
                              hipStream_t stream) {
  const float* x = (const float*)d_in[0];
  const float* w[5]  = {(const float*)d_in[1], (const float*)d_in[4], (const float*)d_in[7],
                        (const float*)d_in[10], (const float*)d_in[13]};
  const float* gg[5] = {(const float*)d_in[2], (const float*)d_in[5], (const float*)d_in[8],
                        (const float*)d_in[11], (const float*)d_in[14]};
  const float* bb[5] = {(const float*)d_in[3], (const float*)d_in[6], (const float*)d_in[9],
                        (const float*)d_in[12], (const float*)d_in[15]};
  float* out = (float*)d_out;

  float* W = (float*)d_ws;
  size_t off = 0;
  float* feat0   = W + off; off += (size_t)B_SZ * N_PTS * 4;   // stride-4 padded
  float* catbuf  = W + off; off += (size_t)8192 * CAT_C;
  int*   idxbuf  = (int*)(W + off); off += (size_t)8192 * KNN_K;
  float* aybuf   = W + off; off += (size_t)8192 * 1024;
  float* mxbuf   = W + off; off += (size_t)8192 * 256;
  float* mnbuf   = W + off; off += (size_t)8192 * 256;
  float* wcbuf   = W + off; off += (size_t)512 * 1024;
  float* sumsbin = W + off; off += (size_t)64 * 512;
  float* sums    = W + off; off += 512;
  float* parts   = W + off; off += (size_t)4 * 64 * 1024;  // L5 tile partials (mx,mn,s1,s2)
  float* x2buf   = W + off; off += 8192;
  float4* packbuf = (float4*)(W + off); off += (size_t)8192 * 32 * 4;  // [b][k4][1024] f4, 4MB

  hipMemsetAsync(feat0, 0, (size_t)B_SZ * N_PTS * 4 * sizeof(float), stream);
  transpose_x<<<(B_SZ * 3 * N_PTS + 255) / 256, 256, 0, stream>>>(x, feat0);

  const int Cs[4] = {4, 64, 64, 128};   // layer-0 padded to 4 (pad=0, values unchanged)
  const int Ks[4] = {3, 64, 64, 128};   // true K for the edge GEMM
  const int Os[4] = {64, 64, 128, 256};
  const int osh[4] = {6, 6, 7, 8};
  const int segin[4] = {0, 0, 64, 128};
  const int segout[4] = {0, 64, 128, 256};

  for (int l = 0; l < 4; ++l) {
    int C = Cs[l], O = Os[l], twoO = 2 * O;
    const float* featin = (l == 0) ? feat0 : (catbuf + segin[l]);
    int lda = (l == 0) ? 4 : CAT_C;
    int C4 = C / 4;

    xnorm_kernel<<<32, 256, 0, stream>>>(featin, lda, C, x2buf);
    pack_kernel<<<(8192 * C4 + 255) / 256, 256, 0, stream>>>(featin, lda, C4, packbuf);
    knn_fused<<<1024, 512, 0, stream>>>(featin, lda, C4, packbuf, x2buf, idxbuf);

    build_wc<<<(Ks[l] * twoO + 255) / 256, 256, 0, stream>>>(w[l], Ks[l], O, wcbuf);
    gemm_kernel<<<dim3(twoO / 64, 8192 / 64), 256, 0, stream>>>(featin, lda, wcbuf, aybuf,
                                                                8192, twoO, Ks[l]);
    hipMemsetAsync(sumsbin, 0, (size_t)64 * 512 * sizeof(float), stream);
    aggregate_kernel<<<2048, 256, 0, stream>>>(aybuf, idxbuf, O, mxbuf, mnbuf, sumsbin);
    reduce_bins<<<1, 256, 0, stream>>>(sumsbin, sums, O);
    finalize_edge<<<(8192 * O) / 256, 256, 0, stream>>>(mxbuf, mnbuf, sums, gg[l], bb[l],
                                                        osh[l], catbuf + segout[l],
                                                        1.0f / (8192.0f * KNN_K));
  }

  // layer 5: h5 = cat * w5^T via split-bf16 MFMA with fused per-tile reduction
  gemm_split_red<<<dim3(1024 / 128, 8192 / 128), 256, 0, stream>>>(catbuf, CAT_C, w[4], 512,
                                                                   parts, 512);
  finalize5_fused<<<8192 / 256, 256, 0, stream>>>(parts, gg[4], bb[4], out);
}

// Round 12
// 535.206 us; speedup vs baseline: 1.3874x; 1.0321x over previous
//
#include <hip/hip_runtime.h>
#include <cstddef>

#define B_SZ 8
#define N_PTS 1024
#define KNN_K 20
#define CAT_C 512
#define BN_EPS 1e-5f

typedef unsigned short u16;
typedef unsigned int u32;
typedef unsigned long long u64;
typedef __bf16 bf16x8 __attribute__((ext_vector_type(8)));
typedef float f32x4 __attribute__((ext_vector_type(4)));

// ---------------- transpose x (B,3,N) -> feat0 (B,N,4) (col 3 pre-zeroed) ----------------
__global__ __launch_bounds__(256) void transpose_x(const float* __restrict__ x,
                                                   float* __restrict__ feat0) {
  int t = blockIdx.x * 256 + threadIdx.x;
  if (t >= B_SZ * 3 * N_PTS) return;
  int b = t / (3 * N_PTS);
  int r = t - b * 3 * N_PTS;
  int c = r / N_PTS;
  int n = r - c * N_PTS;
  feat0[((size_t)(b * N_PTS + n)) * 4 + c] = x[t];
}

// ---------------- squared norms per point ----------------
__global__ __launch_bounds__(256) void xnorm_kernel(const float* __restrict__ feat, int lda,
                                                    int C, float* __restrict__ x2) {
  int p = blockIdx.x * 256 + threadIdx.x;
  if (p >= 8192) return;
  const float* r = feat + (size_t)p * lda;
  float s = 0.f;
  for (int c = 0; c < C; c += 4) {
    float4 v = *(const float4*)(r + c);
    s = fmaf(v.x, v.x, s); s = fmaf(v.y, v.y, s);
    s = fmaf(v.z, v.z, s); s = fmaf(v.w, v.w, s);
  }
  x2[p] = s;
}

// ---------------- pack candidates: feat (b,p,4k4..) -> pack[(b*C4+k4)*1024+p] (float4) ----
__global__ __launch_bounds__(256) void pack_kernel(const float* __restrict__ feat, int lda,
                                                   int C4, float4* __restrict__ packb) {
  int t = blockIdx.x * 256 + threadIdx.x;
  if (t >= 8192 * C4) return;
  int p = t & 1023;
  int bk = t >> 10;
  int k4 = bk % C4, b = bk / C4;
  packb[t] = *(const float4*)(feat + (size_t)(b * 1024 + p) * lda + (k4 << 2));
}

// ---- DPP (hi,lo) u64-max reduce stage; identity old=0 (inline const). Tree HW-verified
// in R10/R11 (bit-exact absmax vs shfl butterfly): row_shr 1/2/4/8 + bcast15/31 -> lane63.
#define RSTAGE(CTRL)                                                                 \
  {                                                                                  \
    u32 nhi = (u32)__builtin_amdgcn_update_dpp(0, (int)chi, (CTRL), 0xF, 0xF, false);\
    u32 nlo = (u32)__builtin_amdgcn_update_dpp(0, (int)clo, (CTRL), 0xF, 0xF, false);\
    bool g = (nhi > chi) || (nhi == chi && nlo > clo);                               \
    chi = g ? nhi : chi;                                                             \
    clo = g ? nlo : clo;                                                             \
  }

// ---------------- fused KNN: distances in-register + top-20 via sort+head-merge --------
// 512 threads = 8 waves; one row per wave; lane holds cols j*64+lane.
// Key = (ordered(val)<<10)|(1023-col): max-order == (value desc, col asc) == proven
// comparator. Per-lane bitonic sort desc (one-time), then 20 rounds of head-merge:
// global max of remaining == max over lane heads (lists sorted) -> identical pop
// sequence to argmax-iterate, ~90 inst/round vs ~515 measured for scan-based rounds.
__global__ __launch_bounds__(512) void knn_fused(const float* __restrict__ feat, int lda,
                                                 int C4, const float4* __restrict__ pack,
                                                 const float* __restrict__ x2,
                                                 int* __restrict__ idxout) {
  __shared__ float4 xms[1024];        // 16 KB: all candidates' current k-slice
  __shared__ float4 xn_sh[8 * 32];    // 4 KB: the block's 8 query rows (C4<=32)
  int tid = threadIdx.x;
  int w = tid >> 6, lane = tid & 63;
  int row0 = blockIdx.x * 8;
  int b = row0 >> 10;
  int row = row0 + w;
  const float4* packB = pack + (size_t)b * C4 * 1024;

  if (tid < 8 * C4) {
    int r = tid / C4, q = tid - r * C4;
    xn_sh[r * 32 + q] = *(const float4*)(feat + (size_t)(row0 + r) * lda + (q << 2));
  }

  float acc[16];
  #pragma unroll
  for (int j = 0; j < 16; ++j) acc[j] = 0.f;

  for (int k4 = 0; k4 < C4; ++k4) {
    xms[tid] = packB[k4 * 1024 + tid];
    xms[tid + 512] = packB[k4 * 1024 + tid + 512];
    __syncthreads();
    float4 xn = xn_sh[w * 32 + k4];
    #pragma unroll
    for (int j = 0; j < 16; ++j) {
      float4 xm = xms[j * 64 + lane];
      acc[j] = fmaf(xn.x, xm.x, acc[j]);
      acc[j] = fmaf(xn.y, xm.y, acc[j]);
      acc[j] = fmaf(xn.z, xm.z, acc[j]);
      acc[j] = fmaf(xn.w, xm.w, acc[j]);
    }
    __syncthreads();
  }

  // epilogue: pd = (2*dot - x2n) - x2m (identical expression to proven kernels),
  // then pack into sortable keys. +0.0f canonicalizes -0 -> +0 so that float
  // equality <=> key equality (only ties matter, and ties are bit-identical).
  const float* x2b = x2 + b * N_PTS;
  float x2n = x2[row];
  u64 K[16];
  #pragma unroll
  for (int j = 0; j < 16; ++j) {
    float v = ((2.f * acc[j] - x2n) - x2b[j * 64 + lane]) + 0.0f;
    u32 u = __float_as_uint(v);
    u ^= (u32)(-(int)(u >> 31)) | 0x80000000u;     // monotone float->uint map
    K[j] = ((u64)u << 10) | (u32)(1023 - (j * 64 + lane));
  }

  // per-lane bitonic sort, descending (16 elements, 80 compare-exchanges)
  #pragma unroll
  for (int kk = 2; kk <= 16; kk <<= 1) {
    #pragma unroll
    for (int jj = kk >> 1; jj > 0; jj >>= 1) {
      #pragma unroll
      for (int i = 0; i < 16; ++i) {
        int l = i ^ jj;
        if (l > i) {
          u64 a = K[i], bq = K[l];
          bool sw = ((i & kk) == 0) ? (a < bq) : (bq < a);
          K[i] = sw ? bq : a;
          K[l] = sw ? a : bq;
        }
      }
    }
  }

  // 20 rounds: wave-max over heads K[0], winner lane pops (shift its sorted list)
  for (int rr = 0; rr < KNN_K; ++rr) {
    u32 chi = (u32)(K[0] >> 32), clo = (u32)K[0];
    RSTAGE(0x111)   // row_shr:1
    RSTAGE(0x112)   // row_shr:2
    RSTAGE(0x114)   // row_shr:4
    RSTAGE(0x118)   // row_shr:8
    RSTAGE(0x142)   // row_bcast15
    RSTAGE(0x143)   // row_bcast31
    u32 whi = (u32)__builtin_amdgcn_readlane((int)chi, 63);
    u32 wlo = (u32)__builtin_amdgcn_readlane((int)clo, 63);

    bool isw = ((u32)(K[0] >> 32) == whi) && ((u32)K[0] == wlo);  // unique winner lane
    #pragma unroll
    for (int m = 0; m < 15; ++m) K[m] = isw ? K[m + 1] : K[m];
    K[15] = isw ? 0ULL : K[15];

    if (lane == 0) idxout[row * KNN_K + rr] = 1023 - (int)(wlo & 1023u);
  }
}

// ---------------- build combined weight Wc (fp32): [w1-w2 | w2], K=C rows x 2O cols ----------------
__global__ __launch_bounds__(256) void build_wc(const float* __restrict__ w, int C, int O,
                                                float* __restrict__ wc) {
  int t = blockIdx.x * 256 + threadIdx.x;
  int twoO = 2 * O;
  if (t >= C * twoO) return;
  int c = t / twoO, j = t - c * twoO;
  float v;
  if (j < O) v = w[j * (2 * C) + c] - w[j * (2 * C) + C + c];
  else       v = w[(j - O) * (2 * C) + C + c];
  wc[t] = v;
}

// ---------------- fp32 GEMM (edge layers): C[M,N] = A[M,K](lda) * B[K,N] ----------------
__global__ __launch_bounds__(256) void gemm_kernel(const float* __restrict__ A, int lda,
                                                   const float* __restrict__ Bm,
                                                   float* __restrict__ Cm,
                                                   int M, int N, int K) {
  __shared__ float As[16][64];
  __shared__ float Bs[16][68];
  int tx = threadIdx.x & 15, ty = threadIdx.x >> 4;
  int bn0 = blockIdx.x * 64, bm0 = blockIdx.y * 64;
  float acc[4][4];
  #pragma unroll
  for (int i = 0; i < 4; ++i)
    #pragma unroll
    for (int j = 0; j < 4; ++j) acc[i][j] = 0.f;

  for (int k0 = 0; k0 < K; k0 += 16) {
    {
      int t = threadIdx.x;
      int m = t >> 2, kb = (t & 3) * 4;
      const float* ap = A + (size_t)(bm0 + m) * lda + k0 + kb;
      #pragma unroll
      for (int i = 0; i < 4; ++i) As[kb + i][m] = (k0 + kb + i < K) ? ap[i] : 0.f;
      int r = t >> 4, c4 = (t & 15) * 4;
      float4 bv = make_float4(0.f, 0.f, 0.f, 0.f);
      if (k0 + r < K) bv = *(const float4*)(Bm + (size_t)(k0 + r) * N + bn0 + c4);
      *(float4*)&Bs[r][c4] = bv;
    }
    __syncthreads();
    #pragma unroll
    for (int k = 0; k < 16; ++k) {
      float a0[4];
      #pragma unroll
      for (int i = 0; i < 4; ++i) a0[i] = As[k][ty * 4 + i];
      float4 bv = *(const float4*)&Bs[k][tx * 4];
      float b0[4] = {bv.x, bv.y, bv.z, bv.w};
      #pragma unroll
      for (int i = 0; i < 4; ++i)
        #pragma unroll
        for (int j = 0; j < 4; ++j) acc[i][j] = fmaf(a0[i], b0[j], acc[i][j]);
    }
    __syncthreads();
  }
  #pragma unroll
  for (int i = 0; i < 4; ++i) {
    float4 v = make_float4(acc[i][0], acc[i][1], acc[i][2], acc[i][3]);
    *(float4*)(Cm + (size_t)(bm0 + ty * 4 + i) * N + bn0 + tx * 4) = v;
  }
}

// ---------------- split fp32 -> bf16 hi/lo MFMA GEMM for layer 5, fused reduction ----------------
__device__ inline void split8(const float* __restrict__ p, bf16x8* hv, bf16x8* lv) {
  float4 a0 = *(const float4*)p, a1 = *(const float4*)(p + 4);
  float v[8] = {a0.x, a0.y, a0.z, a0.w, a1.x, a1.y, a1.z, a1.w};
  bf16x8 h, l;
  #pragma unroll
  for (int j = 0; j < 8; ++j) {
    __bf16 hj = (__bf16)v[j];
    h[j] = hj;
    l[j] = (__bf16)(v[j] - (float)hj);
  }
  *hv = h; *lv = l;
}

__global__ __launch_bounds__(256) void gemm_split_red(const float* __restrict__ A, int lda,
                                                      const float* __restrict__ Bt, int ldb,
                                                      float* __restrict__ parts, int K) {
  __shared__ u16 Ah[128 * 64];
  __shared__ u16 Al[128 * 64];
  __shared__ u16 Bh[128 * 64];
  __shared__ u16 Bl[128 * 64];
  int tid = threadIdx.x;
  int wave = tid >> 6, lane = tid & 63;
  int wr = wave >> 1, wc = wave & 1;
  int bn0 = blockIdx.x * 128, bm0 = blockIdx.y * 128;
  int lrow = lane & 15;
  int kgrp = lane >> 4;

  f32x4 acc[4][4];
  #pragma unroll
  for (int i = 0; i < 4; ++i)
    #pragma unroll
    for (int j = 0; j < 4; ++j) acc[i][j] = (f32x4){0.f, 0.f, 0.f, 0.f};

  for (int k0 = 0; k0 < K; k0 += 64) {
    #pragma unroll
    for (int i = 0; i < 4; ++i) {
      int chunk = tid + i * 256;        // 0..1023
      int row = chunk >> 3;             // 0..127
      int cc = (chunk & 7) * 8;         // fp32 col 0,8,..,56
      int byte = row * 128 + ((cc * 2) ^ ((row & 7) << 4));
      bf16x8 h, l;
      split8(A + (size_t)(bm0 + row) * lda + k0 + cc, &h, &l);
      *(bf16x8*)((char*)Ah + byte) = h;
      *(bf16x8*)((char*)Al + byte) = l;
      split8(Bt + (size_t)(bn0 + row) * ldb + k0 + cc, &h, &l);
      *(bf16x8*)((char*)Bh + byte) = h;
      *(bf16x8*)((char*)Bl + byte) = l;
    }
    __syncthreads();
    #pragma unroll
    for (int kk = 0; kk < 64; kk += 32) {
      int kb = (kk + kgrp * 8) * 2;
      bf16x8 afh[4], afl[4], bfh[4], bfl[4];
      #pragma unroll
      for (int f = 0; f < 4; ++f) {
        int arow = wr * 64 + f * 16 + lrow;
        int abyte = arow * 128 + (kb ^ ((arow & 7) << 4));
        afh[f] = *(const bf16x8*)((const char*)Ah + abyte);
        afl[f] = *(const bf16x8*)((const char*)Al + abyte);
        int brow = wc * 64 + f * 16 + lrow;
        int bbyte = brow * 128 + (kb ^ ((brow & 7) << 4));
        bfh[f] = *(const bf16x8*)((const char*)Bh + bbyte);
        bfl[f] = *(const bf16x8*)((const char*)Bl + bbyte);
      }
      #pragma unroll
      for (int fm = 0; fm < 4; ++fm)
        #pragma unroll
        for (int fn = 0; fn < 4; ++fn) {
          acc[fm][fn] = __builtin_amdgcn_mfma_f32_16x16x32_bf16(afh[fm], bfh[fn], acc[fm][fn], 0, 0, 0);
          acc[fm][fn] = __builtin_amdgcn_mfma_f32_16x16x32_bf16(afl[fm], bfh[fn], acc[fm][fn], 0, 0, 0);
          acc[fm][fn] = __builtin_amdgcn_mfma_f32_16x16x32_bf16(afh[fm], bfl[fn], acc[fm][fn], 0, 0, 0);
        }
    }
    __syncthreads();
  }

  // fused per-tile reduction over the 128 rows
  float* scratch = (float*)Ah;
  int contrib = wr * 4 + kgrp;
  #pragma unroll
  for (int fn = 0; fn < 4; ++fn) {
    float mx = -3.4e38f, mn = 3.4e38f, s1 = 0.f, s2 = 0.f;
    #pragma unroll
    for (int fm = 0; fm < 4; ++fm)
      #pragma unroll
      for (int r = 0; r < 4; ++r) {
        float v = acc[fm][fn][r];
        mx = fmaxf(mx, v); mn = fminf(mn, v);
        s1 += v; s2 = fmaf(v, v, s2);
      }
    int col = wc * 64 + fn * 16 + lrow;
    float* sp = scratch + (contrib * 128 + col) * 4;
    sp[0] = mx; sp[1] = mn; sp[2] = s1; sp[3] = s2;
  }
  __syncthreads();
  if (tid < 128) {
    float mx = -3.4e38f, mn = 3.4e38f, s1 = 0.f, s2 = 0.f;
    #pragma unroll
    for (int c2 = 0; c2 < 8; ++c2) {
      const float* sp = scratch + (c2 * 128 + tid) * 4;
      mx = fmaxf(mx, sp[0]); mn = fminf(mn, sp[1]);
      s1 += sp[2]; s2 += sp[3];
    }
    size_t o = (size_t)blockIdx.y * 1024 + bn0 + tid;
    parts[o] = mx;
    parts[65536 + o] = mn;
    parts[131072 + o] = s1;
    parts[196608 + o] = s2;
  }
}

// ---------------- edge aggregation: h = a + y[idx]; max/min over k + channel sums ----------------
__global__ __launch_bounds__(256) void aggregate_kernel(const float* __restrict__ ay,
                                                        const int* __restrict__ idxb, int O,
                                                        float* __restrict__ mx,
                                                        float* __restrict__ mn,
                                                        float* __restrict__ sumsbin) {
  __shared__ float ls[2][256];
  for (int i = threadIdx.x; i < 512; i += 256) ((float*)ls)[i] = 0.f;
  __syncthreads();

  int warp = threadIdx.x >> 6, lane = threadIdx.x & 63;
  int pt = blockIdx.x * 4 + warp;   // 0..8191
  int b = pt >> 10;
  int twoO = 2 * O;
  int U = O >> 6;
  const float* ayrow = ay + (size_t)pt * twoO;

  float av[4], s1[4], s2[4], vmx[4], vmn[4];
  for (int u = 0; u < U; ++u) {
    av[u] = ayrow[u * 64 + lane];
    s1[u] = 0.f; s2[u] = 0.f; vmx[u] = -3.4e38f; vmn[u] = 3.4e38f;
  }
  const int* ip = idxb + pt * KNN_K;
  for (int k = 0; k < KNN_K; ++k) {
    int j = ip[k];
    const float* yrow = ay + (size_t)(b * N_PTS + j) * twoO + O;
    for (int u = 0; u < U; ++u) {
      float v = av[u] + yrow[u * 64 + lane];
      s1[u] += v; s2[u] = fmaf(v, v, s2[u]);
      vmx[u] = fmaxf(vmx[u], v); vmn[u] = fminf(vmn[u], v);
    }
  }
  for (int u = 0; u < U; ++u) {
    int o = u * 64 + lane;
    mx[(size_t)pt * O + o] = vmx[u];
    mn[(size_t)pt * O + o] = vmn[u];
    atomicAdd(&ls[0][o], s1[u]);
    atomicAdd(&ls[1][o], s2[u]);
  }
  __syncthreads();
  int bin = blockIdx.x & 63;
  float* gb = sumsbin + (size_t)bin * 512;
  for (int o = threadIdx.x; o < O; o += 256) {
    atomicAdd(&gb[o], ls[0][o]);
    atomicAdd(&gb[256 + o], ls[1][o]);
  }
}

__global__ __launch_bounds__(256) void reduce_bins(const float* __restrict__ sumsbin,
                                                   float* __restrict__ sums, int O) {
  int o = threadIdx.x;
  if (o >= O) return;
  float a = 0.f, c = 0.f;
  for (int bin = 0; bin < 64; ++bin) {
    a += sumsbin[bin * 512 + o];
    c += sumsbin[bin * 512 + 256 + o];
  }
  sums[o] = a;
  sums[256 + o] = c;
}

// ---------------- finalize edge layer: BN + relu on (max or min depending on sign) ----------------
__global__ __launch_bounds__(256) void finalize_edge(const float* __restrict__ mx,
                                                     const float* __restrict__ mn,
                                                     const float* __restrict__ sums,
                                                     const float* __restrict__ g,
                                                     const float* __restrict__ beta,
                                                     int oshift,
                                                     float* __restrict__ outseg,
                                                     float cnt_inv) {
  int tid = blockIdx.x * 256 + threadIdx.x;
  int pt = tid >> oshift;
  int o = tid & ((1 << oshift) - 1);
  float s1 = sums[o], s2 = sums[256 + o];
  float mean = s1 * cnt_inv;
  float var = s2 * cnt_inv - mean * mean;
  float rstd = rsqrtf(var + BN_EPS);
  float sc = g[o] * rstd;
  float sel = (sc >= 0.f) ? mx[tid] : mn[tid];
  float v = (sel - mean) * sc + beta[o];
  outseg[(size_t)pt * CAT_C + o] = fmaxf(v, 0.f);
}

// ---------------- layer 5 finalize from tile partials ----------------
__global__ __launch_bounds__(256) void finalize5_fused(const float* __restrict__ parts,
                                                       const float* __restrict__ g,
                                                       const float* __restrict__ beta,
                                                       float* __restrict__ out) {
  int tid = blockIdx.x * 256 + threadIdx.x;   // 0..8191
  int b = tid >> 10, o = tid & 1023;
  const float* pmx = parts;
  const float* pmn = parts + 65536;
  const float* ps1 = parts + 131072;
  const float* ps2 = parts + 196608;
  float s1 = 0.f, s2 = 0.f;
  for (int t = 0; t < 64; ++t) { s1 += ps1[t * 1024 + o]; s2 += ps2[t * 1024 + o]; }
  float mx = -3.4e38f, mn = 3.4e38f;
  #pragma unroll
  for (int t = 0; t < 8; ++t) {
    mx = fmaxf(mx, pmx[(b * 8 + t) * 1024 + o]);
    mn = fminf(mn, pmn[(b * 8 + t) * 1024 + o]);
  }
  float mean = s1 * (1.0f / 8192.0f);
  float var = s2 * (1.0f / 8192.0f) - mean * mean;
  float rstd = rsqrtf(var + BN_EPS);
  float sc = g[o] * rstd;
  float sel = (sc >= 0.f) ? mx : mn;
  float v = (sel - mean) * sc + beta[o];
  out[tid] = fmaxf(v, 0.f);
}

extern "C" void kernel_launch(void* const* d_in, const int* in_sizes, int n_in,
                              void* d_out, int out_size, void* d_ws, size_t ws_size,
                              hipStream_t stream) {
  const float* x = (const float*)d_in[0];
  const float* w[5]  = {(const float*)d_in[1], (const float*)d_in[4], (const float*)d_in[7],
                        (const float*)d_in[10], (const float*)d_in[13]};
  const float* gg[5] = {(const float*)d_in[2], (const float*)d_in[5], (const float*)d_in[8],
                        (const float*)d_in[11], (const float*)d_in[14]};
  const float* bb[5] = {(const float*)d_in[3], (const float*)d_in[6], (const float*)d_in[9],
                        (const float*)d_in[12], (const float*)d_in[15]};
  float* out = (float*)d_out;

  float* W = (float*)d_ws;
  size_t off = 0;
  float* feat0   = W + off; off += (size_t)B_SZ * N_PTS * 4;   // stride-4 padded
  float* catbuf  = W + off; off += (size_t)8192 * CAT_C;
  int*   idxbuf  = (int*)(W + off); off += (size_t)8192 * KNN_K;
  float* aybuf   = W + off; off += (size_t)8192 * 1024;
  float* mxbuf   = W + off; off += (size_t)8192 * 256;
  float* mnbuf   = W + off; off += (size_t)8192 * 256;
  float* wcbuf   = W + off; off += (size_t)512 * 1024;
  float* sumsbin = W + off; off += (size_t)64 * 512;
  float* sums    = W + off; off += 512;
  float* parts   = W + off; off += (size_t)4 * 64 * 1024;  // L5 tile partials (mx,mn,s1,s2)
  float* x2buf   = W + off; off += 8192;
  float4* packbuf = (float4*)(W + off); off += (size_t)8192 * 32 * 4;  // [b][k4][1024] f4, 4MB

  hipMemsetAsync(feat0, 0, (size_t)B_SZ * N_PTS * 4 * sizeof(float), stream);
  transpose_x<<<(B_SZ * 3 * N_PTS + 255) / 256, 256, 0, stream>>>(x, feat0);

  const int Cs[4] = {4, 64, 64, 128};   // layer-0 padded to 4 (pad=0, values unchanged)
  const int Ks[4] = {3, 64, 64, 128};   // true K for the edge GEMM
  const int Os[4] = {64, 64, 128, 256};
  const int osh[4] = {6, 6, 7, 8};
  const int segin[4] = {0, 0, 64, 128};
  const int segout[4] = {0, 64, 128, 256};

  for (int l = 0; l < 4; ++l) {
    int C = Cs[l], O = Os[l], twoO = 2 * O;
    const float* featin = (l == 0) ? feat0 : (catbuf + segin[l]);
    int lda = (l == 0) ? 4 : CAT_C;
    int C4 = C / 4;

    xnorm_kernel<<<32, 256, 0, stream>>>(featin, lda, C, x2buf);
    pack_kernel<<<(8192 * C4 + 255) / 256, 256, 0, stream>>>(featin, lda, C4, packbuf);
    knn_fused<<<1024, 512, 0, stream>>>(featin, lda, C4, packbuf, x2buf, idxbuf);

    build_wc<<<(Ks[l] * twoO + 255) / 256, 256, 0, stream>>>(w[l], Ks[l], O, wcbuf);
    gemm_kernel<<<dim3(twoO / 64, 8192 / 64), 256, 0, stream>>>(featin, lda, wcbuf, aybuf,
                                                                8192, twoO, Ks[l]);
    hipMemsetAsync(sumsbin, 0, (size_t)64 * 512 * sizeof(float), stream);
    aggregate_kernel<<<2048, 256, 0, stream>>>(aybuf, idxbuf, O, mxbuf, mnbuf, sumsbin);
    reduce_bins<<<1, 256, 0, stream>>>(sumsbin, sums, O);
    finalize_edge<<<(8192 * O) / 256, 256, 0, stream>>>(mxbuf, mnbuf, sums, gg[l], bb[l],
                                                        osh[l], catbuf + segout[l],
                                                        1.0f / (8192.0f * KNN_K));
  }

  // layer 5: h5 = cat * w5^T via split-bf16 MFMA with fused per-tile reduction
  gemm_split_red<<<dim3(1024 / 128, 8192 / 128), 256, 0, stream>>>(catbuf, CAT_C, w[4], 512,
                                                                   parts, 512);
  finalize5_fused<<<8192 / 256, 256, 0, stream>>>(parts, gg[4], bb[4], out);
}